// Round 2
// baseline (2830.246 us; speedup 1.0000x reference)
//
#include <hip/hip_runtime.h>
#include <math.h>

#define TPB 256
#define NBLK 6

// deriv normalization: 1/(MIN_D + ln 2)
#define DNORM (1.0f / (0.001f + 0.69314718055994530942f))

// LDS layout (float offsets)
#define W1O 0       // 8*64   = 512
#define W2O 512     // 64*64  = 4096
#define W3O 4608    // 64*124 = 7936
#define B1O 12544   // 64
#define B2O 12608   // 64
#define B3O 12672   // 124
#define WLTOT 12796 // 51184 bytes

__device__ __forceinline__ float leaky(float a) { return a >= 0.f ? a : 0.01f * a; }

__global__ __launch_bounds__(TPB, 2) void flow_kernel(
    const float* __restrict__ X, const float* __restrict__ C4,
    const float* __restrict__ W1, const float* __restrict__ B1,
    const float* __restrict__ W2, const float* __restrict__ B2,
    const float* __restrict__ W3, const float* __restrict__ B3,
    float* __restrict__ JAC, int n)
{
    __shared__ __align__(16) float wl[WLTOT];
    const int tid = threadIdx.x;
    const int gid = blockIdx.x * TPB + tid;   // grid is exact: n % TPB == 0

    const float4 xa = reinterpret_cast<const float4*>(X)[gid * 2 + 0];
    const float4 xb = reinterpret_cast<const float4*>(X)[gid * 2 + 1];
    const float4 cv = reinterpret_cast<const float4*>(C4)[gid];
    float xr0 = xa.x, xr1 = xa.y, xr2 = xa.z, xr3 = xa.w;
    float xr4 = xb.x, xr5 = xb.y, xr6 = xb.z, xr7 = xb.w;

    float jac = 0.f;

    #pragma unroll 1
    for (int blk = 0; blk < NBLK; ++blk) {
        const int p    = blk >> 1;
        const int cbit = (blk & 1) ^ 1;
        const int lm   = (1 << p) - 1;

        int cd[4], td[4];
        #pragma unroll
        for (int j = 0; j < 4; ++j) {
            cd[j] = ((j >> p) << (p + 1)) | (cbit << p) | (j & lm);
            td[j] = ((j >> p) << (p + 1)) | ((cbit ^ 1) << p) | (j & lm);
        }

        const float* w1g = W1 + blk * 512;
        const float* w2g = W2 + blk * 4096;
        const float* w3g = W3 + blk * 7936;
        const float* b1g = B1 + blk * 64;
        const float* b2g = B2 + blk * 64;
        const float* b3g = B3 + blk * 124;

        // ---- stage this block's weights into LDS (fp32, cooperative, coalesced)
        __syncthreads();   // previous block's readers are done
        {
            float4*       wl1 = reinterpret_cast<float4*>(&wl[W1O]);
            float4*       wl2 = reinterpret_cast<float4*>(&wl[W2O]);
            float4*       wl3 = reinterpret_cast<float4*>(&wl[W3O]);
            const float4* g1  = reinterpret_cast<const float4*>(w1g);
            const float4* g2  = reinterpret_cast<const float4*>(w2g);
            const float4* g3  = reinterpret_cast<const float4*>(w3g);
            if (tid < 128) wl1[tid] = g1[tid];                       // 512 f
            #pragma unroll
            for (int i = 0; i < 4; ++i) wl2[i * TPB + tid] = g2[i * TPB + tid];   // 4096 f
            #pragma unroll
            for (int i = 0; i < 7; ++i) wl3[i * TPB + tid] = g3[i * TPB + tid];   // 7168 f
            if (tid < 192) wl3[7 * TPB + tid] = g3[7 * TPB + tid];                // +768 f
            if (tid < 64)                 wl[B1O + tid]        = b1g[tid];
            if (tid >= 64  && tid < 128)  wl[B2O + (tid - 64)] = b2g[tid - 64];
            if (tid >= 128 && tid < 252)  wl[B3O + (tid - 128)] = b3g[tid - 128];
        }
        __syncthreads();

        // ---- gather conditioning inputs: x[cond dims] ++ c
        float xc[8];
        #pragma unroll
        for (int j = 0; j < 4; ++j) {
            const int i = cd[j];
            float v = xr0;
            v = (i == 1) ? xr1 : v; v = (i == 2) ? xr2 : v; v = (i == 3) ? xr3 : v;
            v = (i == 4) ? xr4 : v; v = (i == 5) ? xr5 : v; v = (i == 6) ? xr6 : v;
            v = (i == 7) ? xr7 : v;
            xc[j] = v;
        }
        xc[4] = cv.x; xc[5] = cv.y; xc[6] = cv.z; xc[7] = cv.w;

        // ---- layer 1: 8 -> 64, h1 in VGPRs
        float h1[64];
        #pragma unroll
        for (int u = 0; u < 64; ++u) h1[u] = wl[B1O + u];
        #pragma unroll
        for (int k = 0; k < 8; ++k) {
            const float xk = xc[k];
            #pragma unroll
            for (int u = 0; u < 64; ++u) h1[u] = fmaf(xk, wl[W1O + k * 64 + u], h1[u]);
        }
        #pragma unroll
        for (int u = 0; u < 64; ++u) h1[u] = leaky(h1[u]);

        // ---- layer-3 accumulators (register-resident, all static indexing)
        float o[4][31];
        #pragma unroll
        for (int t = 0; t < 4; ++t)
            #pragma unroll
            for (int j = 0; j < 31; ++j) o[t][j] = wl[B3O + t * 31 + j];

        // ---- fused layer2 + layer3: h2 produced in chunks of 4, applied immediately
        #pragma unroll 1
        for (int uc = 0; uc < 16; ++uc) {
            float acc[4];
            #pragma unroll
            for (int j = 0; j < 4; ++j) acc[j] = wl[B2O + uc * 4 + j];
            #pragma unroll
            for (int k = 0; k < 64; ++k) {
                const float hk = h1[k];
                #pragma unroll
                for (int j = 0; j < 4; ++j)
                    acc[j] = fmaf(hk, wl[W2O + k * 64 + uc * 4 + j], acc[j]);
            }
            #pragma unroll
            for (int kk = 0; kk < 4; ++kk) {
                const float hv = leaky(acc[kk]);
                const int kw = W3O + (uc * 4 + kk) * 124;
                #pragma unroll
                for (int t = 0; t < 4; ++t)
                    #pragma unroll
                    for (int j = 0; j < 31; ++j)
                        o[t][j] = fmaf(hv, wl[kw + t * 31 + j], o[t][j]);
            }
        }

        // ---- trafo-dim inputs + inside flag
        float xt[4];
        #pragma unroll
        for (int j = 0; j < 4; ++j) {
            const int i = td[j];
            float v = xr0;
            v = (i == 1) ? xr1 : v; v = (i == 2) ? xr2 : v; v = (i == 3) ? xr3 : v;
            v = (i == 4) ? xr4 : v; v = (i == 5) ? xr5 : v; v = (i == 6) ? xr6 : v;
            v = (i == 7) ? xr7 : v;
            xt[j] = v;
        }
        const bool inside =
            (xt[0] >= 0.f) && (xt[0] <= 1.f) && (xt[1] >= 0.f) && (xt[1] <= 1.f) &&
            (xt[2] >= 0.f) && (xt[2] <= 1.f) && (xt[3] >= 0.f) && (xt[3] <= 1.f);

        // ---- RQ spline per trafo dim
        #pragma unroll
        for (int t = 0; t < 4; ++t) {
            // widths: softmax(o[t][0..9]) -> cumsum with forced endpoints
            float mw = o[t][0];
            #pragma unroll
            for (int k = 1; k < 10; ++k) mw = fmaxf(mw, o[t][k]);
            float ew[10], sw = 0.f;
            #pragma unroll
            for (int k = 0; k < 10; ++k) { ew[k] = __expf(o[t][k] - mw); sw += ew[k]; }
            const float fw = 0.99f / sw;
            float Cw[11];
            Cw[0] = 0.f;
            #pragma unroll
            for (int k = 1; k <= 10; ++k) Cw[k] = Cw[k - 1] + (0.001f + ew[k - 1] * fw);
            Cw[10] = 1.0f;
            float Wd[10];
            #pragma unroll
            for (int k = 0; k < 10; ++k) Wd[k] = Cw[k + 1] - Cw[k];

            // heights: softmax(o[t][10..19])
            float mh = o[t][10];
            #pragma unroll
            for (int k = 1; k < 10; ++k) mh = fmaxf(mh, o[t][10 + k]);
            float eh[10], sh = 0.f;
            #pragma unroll
            for (int k = 0; k < 10; ++k) { eh[k] = __expf(o[t][10 + k] - mh); sh += eh[k]; }
            const float fh = 0.99f / sh;
            float Ch[11];
            Ch[0] = 0.f;
            #pragma unroll
            for (int k = 1; k <= 10; ++k) Ch[k] = Ch[k - 1] + (0.001f + eh[k - 1] * fh);
            Ch[10] = 1.0f;
            float Hh[10];
            #pragma unroll
            for (int k = 0; k < 10; ++k) Hh[k] = Ch[k + 1] - Ch[k];

            // derivatives: (MIN_D + softplus(o[t][20..30])) / (MIN_D + ln2)
            float dv[11];
            #pragma unroll
            for (int k = 0; k < 11; ++k) {
                const float u = o[t][20 + k];
                const float sp = (u > 15.f) ? u : __logf(1.f + __expf(u));
                dv[k] = (0.001f + sp) * DNORM;
            }

            // bin search + gathers via compare-select scan (inner knots Cw[1..9])
            const float xin = fminf(fmaxf(xt[t], 0.f), 1.f);
            float in_cw = 0.f, in_bw = Wd[0], in_ch = 0.f, in_h = Hh[0];
            float in_d = dv[0], in_dp1 = dv[1];
            #pragma unroll
            for (int k = 1; k < 10; ++k) {
                const bool ge = (xin >= Cw[k]);
                in_cw  = ge ? Cw[k]     : in_cw;
                in_bw  = ge ? Wd[k]     : in_bw;
                in_ch  = ge ? Ch[k]     : in_ch;
                in_h   = ge ? Hh[k]     : in_h;
                in_d   = ge ? dv[k]     : in_d;
                in_dp1 = ge ? dv[k + 1] : in_dp1;
            }

            const float th   = (xin - in_cw) / in_bw;
            const float tomt = th * (1.f - th);
            const float dl   = in_h / in_bw;
            const float nume = in_h * (dl * th * th + in_d * tomt);
            const float deno = dl + (in_d + in_dp1 - 2.f * dl) * tomt;
            const float xout = in_ch + nume / deno;
            const float omt  = 1.f - th;
            const float dnum = dl * dl * (in_dp1 * th * th + 2.f * dl * tomt + in_d * omt * omt);
            const float lad  = __logf(dnum) - 2.f * __logf(deno);

            const float xnew = inside ? xout : xt[t];
            jac += inside ? lad : 0.f;

            const int ti = td[t];
            xr0 = (ti == 0) ? xnew : xr0; xr1 = (ti == 1) ? xnew : xr1;
            xr2 = (ti == 2) ? xnew : xr2; xr3 = (ti == 3) ? xnew : xr3;
            xr4 = (ti == 4) ? xnew : xr4; xr5 = (ti == 5) ? xnew : xr5;
            xr6 = (ti == 6) ? xnew : xr6; xr7 = (ti == 7) ? xnew : xr7;
        }
    }
    JAC[gid] = jac;
}

extern "C" void kernel_launch(void* const* d_in, const int* in_sizes, int n_in,
                              void* d_out, int out_size, void* d_ws, size_t ws_size,
                              hipStream_t stream) {
    (void)n_in; (void)d_ws; (void)ws_size;
    const float* X  = (const float*)d_in[0];
    const float* C4 = (const float*)d_in[1];
    const float* W1 = (const float*)d_in[2];
    const float* B1 = (const float*)d_in[3];
    const float* W2 = (const float*)d_in[4];
    const float* B2 = (const float*)d_in[5];
    const float* W3 = (const float*)d_in[6];
    const float* B3 = (const float*)d_in[7];
    float* out = (float*)d_out;

    const int n = in_sizes[0] / 8;                 // 262144, divisible by TPB
    dim3 grid(n / TPB), block(TPB);
    hipLaunchKernelGGL(flow_kernel, grid, block, 0, stream,
                       X, C4, W1, B1, W2, B2, W3, B3, out, n);
}

// Round 3
// 1046.429 us; speedup vs baseline: 2.7047x; 2.7047x over previous
//
#include <hip/hip_runtime.h>
#include <math.h>

#define TPB 256
#define NBLK 6

// deriv normalization: 1/(MIN_D + ln 2)
#define DNORM (1.0f / (0.001f + 0.69314718055994530942f))

// LDS layout (float offsets)
#define W1TO 0       // W1 transposed [k=64][i=8] = 512
#define W2O  512     // [k=64][u=64] = 4096
#define W3O  4608    // [k=64][j=124] = 7936
#define B1O  12544   // 64
#define B2O  12608   // 64
#define B3O  12672   // 124
#define WLTOT 12796  // 51184 bytes

__device__ __forceinline__ float leaky(float a) { return a >= 0.f ? a : 0.01f * a; }

__device__ __forceinline__ unsigned int bfbits(float f) {
    unsigned int u = __float_as_uint(f);
    return (u + 0x7fffu + ((u >> 16) & 1u)) >> 16;   // RNE to bf16
}

__global__ __launch_bounds__(TPB, 4) void flow_kernel(
    const float* __restrict__ X, const float* __restrict__ C4,
    const float* __restrict__ W1, const float* __restrict__ B1,
    const float* __restrict__ W2, const float* __restrict__ B2,
    const float* __restrict__ W3, const float* __restrict__ B3,
    float* __restrict__ JAC, int n)
{
    __shared__ __align__(16) float wl[WLTOT];
    const int tid = threadIdx.x;
    const int gid = blockIdx.x * TPB + tid;   // n % TPB == 0

    const float4 xa = reinterpret_cast<const float4*>(X)[gid * 2 + 0];
    const float4 xb = reinterpret_cast<const float4*>(X)[gid * 2 + 1];
    const float4 cv = reinterpret_cast<const float4*>(C4)[gid];
    float xr0 = xa.x, xr1 = xa.y, xr2 = xa.z, xr3 = xa.w;
    float xr4 = xb.x, xr5 = xb.y, xr6 = xb.z, xr7 = xb.w;

    float jac = 0.f;

    #pragma unroll 1
    for (int blk = 0; blk < NBLK; ++blk) {
        const int p    = blk >> 1;
        const int cbit = (blk & 1) ^ 1;
        const int tbit = cbit ^ 1;
        const int lm   = (1 << p) - 1;

        // ---- stage this block's weights into LDS
        const float* w1g = W1 + blk * 512;
        const float* w2g = W2 + blk * 4096;
        const float* w3g = W3 + blk * 7936;
        const float* b1g = B1 + blk * 64;
        const float* b2g = B2 + blk * 64;
        const float* b3g = B3 + blk * 124;

        __syncthreads();   // previous iteration's readers done
        {
            // W1 transposed: wl[W1TO + k*8 + i] = W1[i*64 + k]
            int e = tid;
            wl[W1TO + e] = w1g[(e & 7) * 64 + (e >> 3)];
            e = tid + 256;
            wl[W1TO + e] = w1g[(e & 7) * 64 + (e >> 3)];

            float4*       wl2 = reinterpret_cast<float4*>(&wl[W2O]);
            float4*       wl3 = reinterpret_cast<float4*>(&wl[W3O]);
            const float4* g2  = reinterpret_cast<const float4*>(w2g);
            const float4* g3  = reinterpret_cast<const float4*>(w3g);
            #pragma unroll
            for (int i = 0; i < 4; ++i) wl2[i * TPB + tid] = g2[i * TPB + tid];   // 4096 f
            #pragma unroll
            for (int i = 0; i < 7; ++i) wl3[i * TPB + tid] = g3[i * TPB + tid];   // 7168 f
            if (tid < 192) wl3[7 * TPB + tid] = g3[7 * TPB + tid];                // +768 f
            if (tid < 64)                 wl[B1O + tid]         = b1g[tid];
            else if (tid < 128)           wl[B2O + (tid - 64)]  = b2g[tid - 64];
            else if (tid < 252)           wl[B3O + (tid - 128)] = b3g[tid - 128];
        }
        __syncthreads();

        // ---- gather conditioning inputs: x[cond dims] ++ c
        float xc[8];
        #pragma unroll
        for (int j = 0; j < 4; ++j) {
            const int i = ((j >> p) << (p + 1)) | (cbit << p) | (j & lm);
            float v = xr0;
            v = (i == 1) ? xr1 : v; v = (i == 2) ? xr2 : v; v = (i == 3) ? xr3 : v;
            v = (i == 4) ? xr4 : v; v = (i == 5) ? xr5 : v; v = (i == 6) ? xr6 : v;
            v = (i == 7) ? xr7 : v;
            xc[j] = v;
        }
        xc[4] = cv.x; xc[5] = cv.y; xc[6] = cv.z; xc[7] = cv.w;

        // ---- fused layer1+layer2: h1 streamed one element at a time
        float h2f[64];
        #pragma unroll
        for (int u = 0; u < 64; ++u) h2f[u] = wl[B2O + u];
        #pragma unroll 1
        for (int k = 0; k < 64; ++k) {
            float h1k = wl[B1O + k];
            #pragma unroll
            for (int i = 0; i < 8; ++i) h1k = fmaf(xc[i], wl[W1TO + k * 8 + i], h1k);
            h1k = leaky(h1k);
            const int wb = W2O + k * 64;
            #pragma unroll
            for (int u = 0; u < 64; ++u) h2f[u] = fmaf(h1k, wl[wb + u], h2f[u]);
        }
        // pack h2 (post-activation) into bf16x2 registers
        unsigned int h2p[32];
        #pragma unroll
        for (int q = 0; q < 32; ++q)
            h2p[q] = bfbits(leaky(h2f[2 * q])) | (bfbits(leaky(h2f[2 * q + 1])) << 16);

        // ---- trafo-dim inputs + inside flag (pre-update values)
        float xt0, xt1, xt2, xt3;
        {
            float xt[4];
            #pragma unroll
            for (int j = 0; j < 4; ++j) {
                const int i = ((j >> p) << (p + 1)) | (tbit << p) | (j & lm);
                float v = xr0;
                v = (i == 1) ? xr1 : v; v = (i == 2) ? xr2 : v; v = (i == 3) ? xr3 : v;
                v = (i == 4) ? xr4 : v; v = (i == 5) ? xr5 : v; v = (i == 6) ? xr6 : v;
                v = (i == 7) ? xr7 : v;
                xt[j] = v;
            }
            xt0 = xt[0]; xt1 = xt[1]; xt2 = xt[2]; xt3 = xt[3];
        }
        const bool inside =
            (xt0 >= 0.f) && (xt0 <= 1.f) && (xt1 >= 0.f) && (xt1 <= 1.f) &&
            (xt2 >= 0.f) && (xt2 <= 1.f) && (xt3 >= 0.f) && (xt3 <= 1.f);

        // ---- per trafo dim (runtime t): layer-3 slice + RQ spline
        #pragma unroll 1
        for (int t = 0; t < 4; ++t) {
            const int ti  = ((t >> p) << (p + 1)) | (tbit << p) | (t & lm);
            const float xtv = (t == 0) ? xt0 : (t == 1) ? xt1 : (t == 2) ? xt2 : xt3;

            float o[31];
            const int b3b = B3O + t * 31;
            #pragma unroll
            for (int j = 0; j < 31; ++j) o[j] = wl[b3b + j];
            const int w3b = W3O + t * 31;
            #pragma unroll
            for (int k = 0; k < 64; ++k) {
                const unsigned int pk = h2p[k >> 1];
                const float hv = (k & 1) ? __uint_as_float(pk & 0xffff0000u)
                                         : __uint_as_float(pk << 16);
                #pragma unroll
                for (int j = 0; j < 31; ++j)
                    o[j] = fmaf(hv, wl[w3b + k * 124 + j], o[j]);
            }

            // widths: softmax(o[0..9]) -> cumsum with forced endpoints
            float mw = o[0];
            #pragma unroll
            for (int k = 1; k < 10; ++k) mw = fmaxf(mw, o[k]);
            float ew[10], sw = 0.f;
            #pragma unroll
            for (int k = 0; k < 10; ++k) { ew[k] = __expf(o[k] - mw); sw += ew[k]; }
            const float fw = 0.99f / sw;
            float Cw[11];
            Cw[0] = 0.f;
            #pragma unroll
            for (int k = 1; k <= 10; ++k) Cw[k] = Cw[k - 1] + (0.001f + ew[k - 1] * fw);
            Cw[10] = 1.0f;
            float Wd[10];
            #pragma unroll
            for (int k = 0; k < 10; ++k) Wd[k] = Cw[k + 1] - Cw[k];

            // heights: softmax(o[10..19])
            float mh = o[10];
            #pragma unroll
            for (int k = 1; k < 10; ++k) mh = fmaxf(mh, o[10 + k]);
            float eh[10], sh = 0.f;
            #pragma unroll
            for (int k = 0; k < 10; ++k) { eh[k] = __expf(o[10 + k] - mh); sh += eh[k]; }
            const float fh = 0.99f / sh;
            float Ch[11];
            Ch[0] = 0.f;
            #pragma unroll
            for (int k = 1; k <= 10; ++k) Ch[k] = Ch[k - 1] + (0.001f + eh[k - 1] * fh);
            Ch[10] = 1.0f;
            float Hh[10];
            #pragma unroll
            for (int k = 0; k < 10; ++k) Hh[k] = Ch[k + 1] - Ch[k];

            // derivatives: (MIN_D + softplus(o[20..30])) / (MIN_D + ln2)
            float dv[11];
            #pragma unroll
            for (int k = 0; k < 11; ++k) {
                const float u = o[20 + k];
                const float sp = (u > 15.f) ? u : __logf(1.f + __expf(u));
                dv[k] = (0.001f + sp) * DNORM;
            }

            // bin search + gathers via compare-select scan (inner knots Cw[1..9])
            const float xin = fminf(fmaxf(xtv, 0.f), 1.f);
            float in_cw = 0.f, in_bw = Wd[0], in_ch = 0.f, in_h = Hh[0];
            float in_d = dv[0], in_dp1 = dv[1];
            #pragma unroll
            for (int k = 1; k < 10; ++k) {
                const bool ge = (xin >= Cw[k]);
                in_cw  = ge ? Cw[k]     : in_cw;
                in_bw  = ge ? Wd[k]     : in_bw;
                in_ch  = ge ? Ch[k]     : in_ch;
                in_h   = ge ? Hh[k]     : in_h;
                in_d   = ge ? dv[k]     : in_d;
                in_dp1 = ge ? dv[k + 1] : in_dp1;
            }

            const float th   = (xin - in_cw) / in_bw;
            const float tomt = th * (1.f - th);
            const float dl   = in_h / in_bw;
            const float nume = in_h * (dl * th * th + in_d * tomt);
            const float deno = dl + (in_d + in_dp1 - 2.f * dl) * tomt;
            const float xout = in_ch + nume / deno;
            const float omt  = 1.f - th;
            const float dnum = dl * dl * (in_dp1 * th * th + 2.f * dl * tomt + in_d * omt * omt);
            const float lad  = __logf(dnum) - 2.f * __logf(deno);

            const float xnew = inside ? xout : xtv;
            jac += inside ? lad : 0.f;

            xr0 = (ti == 0) ? xnew : xr0; xr1 = (ti == 1) ? xnew : xr1;
            xr2 = (ti == 2) ? xnew : xr2; xr3 = (ti == 3) ? xnew : xr3;
            xr4 = (ti == 4) ? xnew : xr4; xr5 = (ti == 5) ? xnew : xr5;
            xr6 = (ti == 6) ? xnew : xr6; xr7 = (ti == 7) ? xnew : xr7;
        }
    }
    JAC[gid] = jac;
}

extern "C" void kernel_launch(void* const* d_in, const int* in_sizes, int n_in,
                              void* d_out, int out_size, void* d_ws, size_t ws_size,
                              hipStream_t stream) {
    (void)n_in; (void)d_ws; (void)ws_size;
    const float* X  = (const float*)d_in[0];
    const float* C4 = (const float*)d_in[1];
    const float* W1 = (const float*)d_in[2];
    const float* B1 = (const float*)d_in[3];
    const float* W2 = (const float*)d_in[4];
    const float* B2 = (const float*)d_in[5];
    const float* W3 = (const float*)d_in[6];
    const float* B3 = (const float*)d_in[7];
    float* out = (float*)d_out;

    const int n = in_sizes[0] / 8;                 // 262144, divisible by TPB
    dim3 grid(n / TPB), block(TPB);
    hipLaunchKernelGGL(flow_kernel, grid, block, 0, stream,
                       X, C4, W1, B1, W2, B2, W3, B3, out, n);
}

// Round 6
// 318.944 us; speedup vs baseline: 8.8738x; 3.2809x over previous
//
#include <hip/hip_runtime.h>
#include <math.h>

#define TPB 512
#define NBLK 6
#define DNORM (1.0f / (0.001f + 0.69314718055994530942f))

typedef float  f32x4  __attribute__((ext_vector_type(4)));
typedef short  bf16x8 __attribute__((ext_vector_type(8)));

#define MFMA16(A, B, C) __builtin_amdgcn_mfma_f32_16x16x32_bf16((A), (B), (C), 0, 0, 0)

// d_ws per-flow-block region: stride 32768 u16 = 64KB
//   hi fragments : u16 [0 .. 14335]   (w1f 2048 | w2f 4096 | w3f 8192)
//   lo fragments : u16 [14336 .. 28671] (same structure)
//   bias         : f32 [256] at u16 offset 28672 (b1 64 | b2 64 | b3p 128)
//   pad          : u16 [29184 .. 32767] staged but never read
// total d_ws = 6 * 65536 B = 384 KB

__device__ __forceinline__ float leaky(float a) { return a >= 0.f ? a : 0.01f * a; }

__device__ __forceinline__ unsigned int bfbits(float f) {
    unsigned int u = __float_as_uint(f);
    return (u + 0x7fffu + ((u >> 16) & 1u)) >> 16;   // RNE to bf16
}
__device__ __forceinline__ float bf2f(unsigned int h) {
    return __uint_as_float(h << 16);
}

__global__ void prep_kernel(const float* __restrict__ W1, const float* __restrict__ B1,
                            const float* __restrict__ W2, const float* __restrict__ B2,
                            const float* __restrict__ W3, const float* __restrict__ B3,
                            unsigned short* __restrict__ wsf)
{
    const int blk = blockIdx.x;
    const int tid = threadIdx.x;          // 1024 threads
    unsigned short* base = wsf + blk * 32768;
    const float* w1 = W1 + blk * 512;
    const float* w2 = W2 + blk * 4096;
    const float* w3 = W3 + blk * 7936;

    for (int e = tid; e < 2048; e += 1024) {
        const int tile = e >> 9, lane = (e >> 3) & 63, i = e & 7;
        const int k = (lane >> 4) * 8 + i, col = tile * 16 + (lane & 15);
        const float f = (k < 8) ? w1[k * 64 + col] : 0.f;
        const unsigned int uh = bfbits(f);
        base[e]         = (unsigned short)uh;
        base[14336 + e] = (unsigned short)bfbits(f - bf2f(uh));
    }
    for (int e = tid; e < 4096; e += 1024) {
        const int ks = e >> 11, tile = (e >> 9) & 3, lane = (e >> 3) & 63, i = e & 7;
        const int k = ks * 32 + (lane >> 4) * 8 + i, col = tile * 16 + (lane & 15);
        const float f = w2[k * 64 + col];
        const unsigned int uh = bfbits(f);
        base[2048 + e]         = (unsigned short)uh;
        base[14336 + 2048 + e] = (unsigned short)bfbits(f - bf2f(uh));
    }
    for (int e = tid; e < 8192; e += 1024) {
        const int ks = e >> 12, tile = (e >> 9) & 7, lane = (e >> 3) & 63, i = e & 7;
        const int k = ks * 32 + (lane >> 4) * 8 + i, col = tile * 16 + (lane & 15);
        const float f = (col < 124) ? w3[k * 124 + col] : 0.f;
        const unsigned int uh = bfbits(f);
        base[6144 + e]         = (unsigned short)uh;
        base[14336 + 6144 + e] = (unsigned short)bfbits(f - bf2f(uh));
    }
    float* bb = reinterpret_cast<float*>(base + 28672);
    if (tid < 64) { bb[tid] = B1[blk * 64 + tid]; bb[64 + tid] = B2[blk * 64 + tid]; }
    if (tid >= 128 && tid < 256) {
        const int j = tid - 128;
        bb[128 + j] = (j < 124) ? B3[blk * 124 + j] : 0.f;
    }
}

__global__ __launch_bounds__(TPB, 2) void flow_kernel(
    const float* __restrict__ X, const float* __restrict__ C4,
    const unsigned short* __restrict__ WSF, float* __restrict__ JAC)
{
    // 136 KB static LDS -> 1 WG/CU (2 waves/SIMD)
    __shared__ __align__(16) unsigned short s_w[32768];   // 64KB: hi | lo | bias(f32)
    __shared__ __align__(16) unsigned char  s_u[67584];   // union{ h_hi[128][72] + h_lo[128][72], o[8][16][132] f32 }
    __shared__ __align__(16) float          s_x[1024];    // [128][8] f32 exact x state
    __shared__ __align__(16) float          s_c[512];     // [128][4] f32

    unsigned short* s_hh = reinterpret_cast<unsigned short*>(s_u);             // [128][72]
    unsigned short* s_hl = reinterpret_cast<unsigned short*>(s_u + 18432);     // [128][72]

    const int tid   = threadIdx.x;
    const int wv    = tid >> 6;        // 0..7
    const int ln    = tid & 63;
    const int col16 = ln & 15;         // MFMA col / sample slot
    const int g     = ln >> 4;         // k-group / trafo slot
    const int srow  = wv * 16 + col16; // this lane's sample row (0..127)

    // ---- initial x / c loads (2048 B + 1024 B per half... 128 samples)
    reinterpret_cast<float2*>(s_x)[tid] =
        reinterpret_cast<const float2*>(X)[(size_t)blockIdx.x * 512 + tid];
    if (tid < 512) s_c[tid] = C4[(size_t)blockIdx.x * 512 + tid];

    // ---- stage block 0 weights (64 chunks x 1024B; wave wv takes chunks r*8+wv)
    {
        const unsigned short* gsrc = WSF;
        #pragma unroll
        for (int r = 0; r < 8; ++r) {
            const int off = (r * 8 + wv) * 512;   // u16 units, wave-uniform
            __builtin_amdgcn_global_load_lds(
                (const __attribute__((address_space(1))) unsigned int*)(gsrc + off + ln * 8),
                (__attribute__((address_space(3))) unsigned int*)(&s_w[off]),
                16, 0, 0);
        }
    }

    const float* bias = reinterpret_cast<const float*>(&s_w[28672]);
    float jacl = 0.f;

    #pragma unroll 1
    for (int blk = 0; blk < NBLK; ++blk) {
        __syncthreads();   // staged weights visible; union region free (prev spline done)

        const int p  = blk >> 1;
        const int cb = (blk & 1) ^ 1;
        const int tb = blk & 1;
        const int lm = (1 << p) - 1;

        // ---- conditioning inputs: x[cond dims] ++ c, split hi/lo
        float xcf[8];
        #pragma unroll
        for (int j = 0; j < 4; ++j) {
            const int cd = ((j >> p) << (p + 1)) | (cb << p) | (j & lm);
            xcf[j] = s_x[srow * 8 + cd];
        }
        {
            const float4 cvv = *reinterpret_cast<const float4*>(&s_c[srow * 4]);
            xcf[4] = cvv.x; xcf[5] = cvv.y; xcf[6] = cvv.z; xcf[7] = cvv.w;
        }
        union { unsigned int u[4]; bf16x8 v; } ah, al;
        #pragma unroll
        for (int q = 0; q < 4; ++q) {
            unsigned int h0 = bfbits(xcf[2 * q]);
            unsigned int l0 = bfbits(xcf[2 * q] - bf2f(h0));
            unsigned int h1 = bfbits(xcf[2 * q + 1]);
            unsigned int l1 = bfbits(xcf[2 * q + 1] - bf2f(h1));
            ah.u[q] = (ln < 16) ? (h0 | (h1 << 16)) : 0u;
            al.u[q] = (ln < 16) ? (l0 | (l1 << 16)) : 0u;
        }

        // ---- L1: 8 -> 64 (K=8 padded to 32), 3-term split product
        #pragma unroll
        for (int tile = 0; tile < 4; ++tile) {
            const float bv = bias[tile * 16 + col16];
            f32x4 a1 = (f32x4){bv, bv, bv, bv};
            const bf16x8 bh = *reinterpret_cast<const bf16x8*>(&s_w[tile * 512 + ln * 8]);
            const bf16x8 bl = *reinterpret_cast<const bf16x8*>(&s_w[14336 + tile * 512 + ln * 8]);
            a1 = MFMA16(al.v, bh, a1);
            a1 = MFMA16(ah.v, bl, a1);
            a1 = MFMA16(ah.v, bh, a1);
            #pragma unroll
            for (int r = 0; r < 4; ++r) {
                const float hv = leaky(a1[r]);
                const unsigned int hh = bfbits(hv);
                const unsigned int hl = bfbits(hv - bf2f(hh));
                const int idx = (wv * 16 + g * 4 + r) * 72 + tile * 16 + col16;
                s_hh[idx] = (unsigned short)hh;
                s_hl[idx] = (unsigned short)hl;
            }
        }

        // ---- L2: 64 -> 64
        f32x4 acc2[4];
        #pragma unroll
        for (int tile = 0; tile < 4; ++tile) {
            const float bv = bias[64 + tile * 16 + col16];
            acc2[tile] = (f32x4){bv, bv, bv, bv};
        }
        #pragma unroll
        for (int ks = 0; ks < 2; ++ks) {
            const bf16x8 a2h = *reinterpret_cast<const bf16x8*>(&s_hh[srow * 72 + ks * 32 + g * 8]);
            const bf16x8 a2l = *reinterpret_cast<const bf16x8*>(&s_hl[srow * 72 + ks * 32 + g * 8]);
            #pragma unroll
            for (int tile = 0; tile < 4; ++tile) {
                const int fo = 2048 + (ks * 4 + tile) * 512 + ln * 8;
                const bf16x8 bh = *reinterpret_cast<const bf16x8*>(&s_w[fo]);
                const bf16x8 bl = *reinterpret_cast<const bf16x8*>(&s_w[14336 + fo]);
                acc2[tile] = MFMA16(a2l, bh, acc2[tile]);
                acc2[tile] = MFMA16(a2h, bl, acc2[tile]);
                acc2[tile] = MFMA16(a2h, bh, acc2[tile]);
            }
        }
        #pragma unroll
        for (int tile = 0; tile < 4; ++tile)
            #pragma unroll
            for (int r = 0; r < 4; ++r) {
                const float hv = leaky(acc2[tile][r]);
                const unsigned int hh = bfbits(hv);
                const unsigned int hl = bfbits(hv - bf2f(hh));
                const int idx = (wv * 16 + g * 4 + r) * 72 + tile * 16 + col16;
                s_hh[idx] = (unsigned short)hh;
                s_hl[idx] = (unsigned short)hl;
            }

        // ---- L3: 64 -> 124 (padded 128)
        f32x4 acc3[8];
        #pragma unroll
        for (int tile = 0; tile < 8; ++tile) {
            const float bv = bias[128 + tile * 16 + col16];
            acc3[tile] = (f32x4){bv, bv, bv, bv};
        }
        #pragma unroll
        for (int ks = 0; ks < 2; ++ks) {
            const bf16x8 a3h = *reinterpret_cast<const bf16x8*>(&s_hh[srow * 72 + ks * 32 + g * 8]);
            const bf16x8 a3l = *reinterpret_cast<const bf16x8*>(&s_hl[srow * 72 + ks * 32 + g * 8]);
            #pragma unroll
            for (int tile = 0; tile < 8; ++tile) {
                const int fo = 6144 + (ks * 8 + tile) * 512 + ln * 8;
                const bf16x8 bh = *reinterpret_cast<const bf16x8*>(&s_w[fo]);
                const bf16x8 bl = *reinterpret_cast<const bf16x8*>(&s_w[14336 + fo]);
                acc3[tile] = MFMA16(a3l, bh, acc3[tile]);
                acc3[tile] = MFMA16(a3h, bl, acc3[tile]);
                acc3[tile] = MFMA16(a3h, bh, acc3[tile]);
            }
        }

        __syncthreads();   // all waves done reading s_w and s_h planes

        // ---- issue next block's weight staging (overlaps o-transpose + spline)
        if (blk < NBLK - 1) {
            const unsigned short* gsrc = WSF + (blk + 1) * 32768;
            #pragma unroll
            for (int r = 0; r < 8; ++r) {
                const int off = (r * 8 + wv) * 512;
                __builtin_amdgcn_global_load_lds(
                    (const __attribute__((address_space(1))) unsigned int*)(gsrc + off + ln * 8),
                    (__attribute__((address_space(3))) unsigned int*)(&s_w[off]),
                    16, 0, 0);
            }
        }

        // ---- o transpose into per-wave union region [16][132] f32
        float* op = reinterpret_cast<float*>(s_u) + wv * 2112;
        #pragma unroll
        for (int tile = 0; tile < 8; ++tile)
            #pragma unroll
            for (int r = 0; r < 4; ++r)
                op[(g * 4 + r) * 132 + tile * 16 + col16] = acc3[tile][r];

        // ---- spline: lane = (sample col16, trafo slot g)
        float xt[4];
        #pragma unroll
        for (int j = 0; j < 4; ++j) {
            const int td = ((j >> p) << (p + 1)) | (tb << p) | (j & lm);
            xt[j] = s_x[srow * 8 + td];
        }
        const bool inside =
            (xt[0] >= 0.f) && (xt[0] <= 1.f) && (xt[1] >= 0.f) && (xt[1] <= 1.f) &&
            (xt[2] >= 0.f) && (xt[2] <= 1.f) && (xt[3] >= 0.f) && (xt[3] <= 1.f);
        float xtv = (g == 1) ? xt[1] : xt[0];
        xtv = (g == 2) ? xt[2] : xtv;
        xtv = (g == 3) ? xt[3] : xtv;
        const int ti = ((g >> p) << (p + 1)) | (tb << p) | (g & lm);

        float ov[31];
        {
            const float* ob = op + col16 * 132 + g * 31;
            #pragma unroll
            for (int j = 0; j < 31; ++j) ov[j] = ob[j];
        }

        // widths
        float mw = ov[0];
        #pragma unroll
        for (int k = 1; k < 10; ++k) mw = fmaxf(mw, ov[k]);
        float ew[10], sw = 0.f;
        #pragma unroll
        for (int k = 0; k < 10; ++k) { ew[k] = __expf(ov[k] - mw); sw += ew[k]; }
        const float fw = 0.99f / sw;
        float Cw[11];
        Cw[0] = 0.f;
        #pragma unroll
        for (int k = 1; k <= 10; ++k) Cw[k] = Cw[k - 1] + (0.001f + ew[k - 1] * fw);
        Cw[10] = 1.0f;
        float Wd[10];
        #pragma unroll
        for (int k = 0; k < 10; ++k) Wd[k] = Cw[k + 1] - Cw[k];

        // heights
        float mh = ov[10];
        #pragma unroll
        for (int k = 1; k < 10; ++k) mh = fmaxf(mh, ov[10 + k]);
        float eh[10], sh = 0.f;
        #pragma unroll
        for (int k = 0; k < 10; ++k) { eh[k] = __expf(ov[10 + k] - mh); sh += eh[k]; }
        const float fh = 0.99f / sh;
        float Ch[11];
        Ch[0] = 0.f;
        #pragma unroll
        for (int k = 1; k <= 10; ++k) Ch[k] = Ch[k - 1] + (0.001f + eh[k - 1] * fh);
        Ch[10] = 1.0f;
        float Hh[10];
        #pragma unroll
        for (int k = 0; k < 10; ++k) Hh[k] = Ch[k + 1] - Ch[k];

        // derivatives
        float dv[11];
        #pragma unroll
        for (int k = 0; k < 11; ++k) {
            const float u = ov[20 + k];
            const float sp = (u > 15.f) ? u : __logf(1.f + __expf(u));
            dv[k] = (0.001f + sp) * DNORM;
        }

        // bin search + gathers via compare-select scan
        const float xin = fminf(fmaxf(xtv, 0.f), 1.f);
        float in_cw = 0.f, in_bw = Wd[0], in_ch = 0.f, in_h = Hh[0];
        float in_d = dv[0], in_dp1 = dv[1];
        #pragma unroll
        for (int k = 1; k < 10; ++k) {
            const bool ge = (xin >= Cw[k]);
            in_cw  = ge ? Cw[k]     : in_cw;
            in_bw  = ge ? Wd[k]     : in_bw;
            in_ch  = ge ? Ch[k]     : in_ch;
            in_h   = ge ? Hh[k]     : in_h;
            in_d   = ge ? dv[k]     : in_d;
            in_dp1 = ge ? dv[k + 1] : in_dp1;
        }

        const float th   = (xin - in_cw) / in_bw;
        const float tomt = th * (1.f - th);
        const float dl   = in_h / in_bw;
        const float nume = in_h * (dl * th * th + in_d * tomt);
        const float deno = dl + (in_d + in_dp1 - 2.f * dl) * tomt;
        const float xout = in_ch + nume / deno;
        const float omt  = 1.f - th;
        const float dnum = dl * dl * (in_dp1 * th * th + 2.f * dl * tomt + in_d * omt * omt);
        const float lad  = __logf(dnum) - 2.f * __logf(deno);

        jacl += inside ? lad : 0.f;
        s_x[srow * 8 + ti] = inside ? xout : xtv;
    }

    // jac = sum over the 4 trafo-slot lanes of each sample
    jacl += __shfl_xor(jacl, 16);
    jacl += __shfl_xor(jacl, 32);
    if (ln < 16)
        JAC[(size_t)blockIdx.x * 128 + wv * 16 + ln] = jacl;
}

extern "C" void kernel_launch(void* const* d_in, const int* in_sizes, int n_in,
                              void* d_out, int out_size, void* d_ws, size_t ws_size,
                              hipStream_t stream) {
    (void)n_in; (void)ws_size;
    const float* X  = (const float*)d_in[0];
    const float* C4 = (const float*)d_in[1];
    const float* W1 = (const float*)d_in[2];
    const float* B1 = (const float*)d_in[3];
    const float* W2 = (const float*)d_in[4];
    const float* B2 = (const float*)d_in[5];
    const float* W3 = (const float*)d_in[6];
    const float* B3 = (const float*)d_in[7];
    float* out = (float*)d_out;
    unsigned short* wsf = (unsigned short*)d_ws;   // 6 * 32768 u16 = 384 KB

    hipLaunchKernelGGL(prep_kernel, dim3(NBLK), dim3(1024), 0, stream,
                       W1, B1, W2, B2, W3, B3, wsf);

    const int n = in_sizes[0] / 8;                 // 262144
    hipLaunchKernelGGL(flow_kernel, dim3(n / 128), dim3(TPB), 0, stream,
                       X, C4, wsf, out);
}

// Round 7
// 276.346 us; speedup vs baseline: 10.2417x; 1.1541x over previous
//
#include <hip/hip_runtime.h>
#include <math.h>

#define TPB 512
#define NBLK 6
#define DNORM (1.0f / (0.001f + 0.69314718055994530942f))

typedef float  f32x4  __attribute__((ext_vector_type(4)));
typedef short  bf16x8 __attribute__((ext_vector_type(8)));

#define MFMA16(A, B, C) __builtin_amdgcn_mfma_f32_16x16x32_bf16((A), (B), (C), 0, 0, 0)

// d_ws per-flow-block region: stride 32768 u16 = 64KB (content 29184 u16)
//   hi fragments : u16 [0 .. 14335]     (w1f 2048 | w2f 4096 | w3f 8192)
//   lo fragments : u16 [14336 .. 28671] (same structure)
//   bias         : f32 [256] at u16 offset 28672 (b1 64 | b2 64 | b3p 128)

__device__ __forceinline__ float leaky(float a) { return a >= 0.f ? a : 0.01f * a; }

__device__ __forceinline__ unsigned int bfbits(float f) {
    unsigned int u = __float_as_uint(f);
    return (u + 0x7fffu + ((u >> 16) & 1u)) >> 16;   // RNE to bf16
}
__device__ __forceinline__ float bf2f(unsigned int h) {
    return __uint_as_float(h << 16);
}
__device__ __forceinline__ unsigned int pk2(float a, float b) {
    return bfbits(a) | (bfbits(b) << 16);
}

__global__ void prep_kernel(const float* __restrict__ W1, const float* __restrict__ B1,
                            const float* __restrict__ W2, const float* __restrict__ B2,
                            const float* __restrict__ W3, const float* __restrict__ B3,
                            unsigned short* __restrict__ wsf)
{
    const int blk = blockIdx.x;
    const int tid = threadIdx.x;          // 1024 threads
    unsigned short* base = wsf + blk * 32768;
    const float* w1 = W1 + blk * 512;
    const float* w2 = W2 + blk * 4096;
    const float* w3 = W3 + blk * 7936;

    for (int e = tid; e < 2048; e += 1024) {
        const int tile = e >> 9, lane = (e >> 3) & 63, i = e & 7;
        const int k = (lane >> 4) * 8 + i, col = tile * 16 + (lane & 15);
        const float f = (k < 8) ? w1[k * 64 + col] : 0.f;
        const unsigned int uh = bfbits(f);
        base[e]         = (unsigned short)uh;
        base[14336 + e] = (unsigned short)bfbits(f - bf2f(uh));
    }
    for (int e = tid; e < 4096; e += 1024) {
        const int ks = e >> 11, tile = (e >> 9) & 3, lane = (e >> 3) & 63, i = e & 7;
        const int k = ks * 32 + (lane >> 4) * 8 + i, col = tile * 16 + (lane & 15);
        const float f = w2[k * 64 + col];
        const unsigned int uh = bfbits(f);
        base[2048 + e]         = (unsigned short)uh;
        base[14336 + 2048 + e] = (unsigned short)bfbits(f - bf2f(uh));
    }
    for (int e = tid; e < 8192; e += 1024) {
        const int ks = e >> 12, tile = (e >> 9) & 7, lane = (e >> 3) & 63, i = e & 7;
        const int k = ks * 32 + (lane >> 4) * 8 + i, col = tile * 16 + (lane & 15);
        const float f = (col < 124) ? w3[k * 124 + col] : 0.f;
        const unsigned int uh = bfbits(f);
        base[6144 + e]         = (unsigned short)uh;
        base[14336 + 6144 + e] = (unsigned short)bfbits(f - bf2f(uh));
    }
    float* bb = reinterpret_cast<float*>(base + 28672);
    if (tid < 64) { bb[tid] = B1[blk * 64 + tid]; bb[64 + tid] = B2[blk * 64 + tid]; }
    if (tid >= 128 && tid < 256) {
        const int j = tid - 128;
        bb[128 + j] = (j < 124) ? B3[blk * 124 + j] : 0.f;
    }
}

__global__ __launch_bounds__(TPB, 2) void flow_kernel(
    const float* __restrict__ X, const float* __restrict__ C4,
    const unsigned short* __restrict__ WSF, float* __restrict__ JAC)
{
    // 127 KB static LDS -> 1 WG/CU (8 waves/CU)
    __shared__ __align__(16) unsigned short s_w[29184];  // 57KB: hi | lo | bias(f32)
    __shared__ __align__(16) unsigned char  s_u[67584];  // per-wave 8448B: union{ h[16][72] bf16, o[16][132] f32 }
    __shared__ __align__(16) float          s_x[1024];   // [128][8] f32 exact x state

    const int tid   = threadIdx.x;
    const int wv    = tid >> 6;        // 0..7
    const int ln    = tid & 63;
    const int col16 = ln & 15;         // MFMA col = SAMPLE slot (D^T layout)
    const int g     = ln >> 4;         // k-group / feature-row group / trafo slot
    const int srow  = wv * 16 + col16; // this lane's sample row (0..127)

    unsigned short* hh = reinterpret_cast<unsigned short*>(s_u + wv * 8448); // [16][72] bf16
    float*          op = reinterpret_cast<float*>(s_u + wv * 8448);          // [16][132] f32 (overlays hh)

    // ---- initial x load -> LDS; c stays in registers (per-lane, L1-served)
    reinterpret_cast<float2*>(s_x)[tid] =
        reinterpret_cast<const float2*>(X)[(size_t)blockIdx.x * 512 + tid];
    const float4 cvv = reinterpret_cast<const float4*>(C4)[(size_t)blockIdx.x * 128 + srow];

    // ---- stage block 0 weights (57 chunks x 1024B)
    {
        const unsigned short* gsrc = WSF;
        #pragma unroll
        for (int r = 0; r < 7; ++r) {
            const int off = (r * 8 + wv) * 512;   // u16 units, wave-uniform
            __builtin_amdgcn_global_load_lds(
                (const __attribute__((address_space(1))) unsigned int*)(gsrc + off + ln * 8),
                (__attribute__((address_space(3))) unsigned int*)(&s_w[off]),
                16, 0, 0);
        }
        if (wv == 0) {
            const int off = 56 * 512;
            __builtin_amdgcn_global_load_lds(
                (const __attribute__((address_space(1))) unsigned int*)(gsrc + off + ln * 8),
                (__attribute__((address_space(3))) unsigned int*)(&s_w[off]),
                16, 0, 0);
        }
    }

    const float* biasf = reinterpret_cast<const float*>(&s_w[28672]);
    const int fB = g * 4;              // this lane's feature offset within a 16-row tile
    float jacl = 0.f;

    #pragma unroll 1
    for (int blk = 0; blk < NBLK; ++blk) {
        __syncthreads();   // staged weights visible; per-wave scratch free

        const int p  = blk >> 1;
        const int cb = (blk & 1) ^ 1;
        const int tb = blk & 1;
        const int lm = (1 << p) - 1;

        // ---- conditioning inputs: x[cond dims] ++ c, hi/lo split (B-operand, k<8 => g==0)
        float xcf[8];
        #pragma unroll
        for (int j = 0; j < 4; ++j) {
            const int cd = ((j >> p) << (p + 1)) | (cb << p) | (j & lm);
            xcf[j] = s_x[srow * 8 + cd];
        }
        xcf[4] = cvv.x; xcf[5] = cvv.y; xcf[6] = cvv.z; xcf[7] = cvv.w;

        union { unsigned int u[4]; bf16x8 v; } bxh, bxl;
        #pragma unroll
        for (int q = 0; q < 4; ++q) {
            const unsigned int h0 = bfbits(xcf[2 * q]);
            const unsigned int l0 = bfbits(xcf[2 * q] - bf2f(h0));
            const unsigned int h1 = bfbits(xcf[2 * q + 1]);
            const unsigned int l1 = bfbits(xcf[2 * q + 1] - bf2f(h1));
            bxh.u[q] = (g == 0) ? (h0 | (h1 << 16)) : 0u;
            bxl.u[q] = (g == 0) ? (l0 | (l1 << 16)) : 0u;
        }

        // ---- L1: D^T = W1^T(16f x 32k) * x(32k x 16s); lane holds 4 consecutive features
        #pragma unroll
        for (int tile = 0; tile < 4; ++tile) {
            f32x4 a1 = *reinterpret_cast<const f32x4*>(&biasf[tile * 16 + fB]);
            const bf16x8 wh = *reinterpret_cast<const bf16x8*>(&s_w[tile * 512 + ln * 8]);
            const bf16x8 wl = *reinterpret_cast<const bf16x8*>(&s_w[14336 + tile * 512 + ln * 8]);
            a1 = MFMA16(wl, bxh.v, a1);
            a1 = MFMA16(wh, bxl.v, a1);
            a1 = MFMA16(wh, bxh.v, a1);
            uint2 pw;
            pw.x = pk2(leaky(a1[0]), leaky(a1[1]));
            pw.y = pk2(leaky(a1[2]), leaky(a1[3]));
            *reinterpret_cast<uint2*>(&hh[col16 * 72 + tile * 16 + fB]) = pw;  // ds_write_b64
        }

        // ---- L2: 64 -> 64 (h1 bf16-only; W2 split)
        f32x4 acc2[4];
        #pragma unroll
        for (int tile = 0; tile < 4; ++tile)
            acc2[tile] = *reinterpret_cast<const f32x4*>(&biasf[64 + tile * 16 + fB]);
        #pragma unroll
        for (int ks = 0; ks < 2; ++ks) {
            const bf16x8 hf = *reinterpret_cast<const bf16x8*>(&hh[col16 * 72 + ks * 32 + g * 8]);
            #pragma unroll
            for (int tile = 0; tile < 4; ++tile) {
                const int fo = 2048 + (ks * 4 + tile) * 512 + ln * 8;
                const bf16x8 wh = *reinterpret_cast<const bf16x8*>(&s_w[fo]);
                const bf16x8 wl = *reinterpret_cast<const bf16x8*>(&s_w[14336 + fo]);
                acc2[tile] = MFMA16(wl, hf, acc2[tile]);
                acc2[tile] = MFMA16(wh, hf, acc2[tile]);
            }
        }
        #pragma unroll
        for (int tile = 0; tile < 4; ++tile) {
            uint2 pw;
            pw.x = pk2(leaky(acc2[tile][0]), leaky(acc2[tile][1]));
            pw.y = pk2(leaky(acc2[tile][2]), leaky(acc2[tile][3]));
            *reinterpret_cast<uint2*>(&hh[col16 * 72 + tile * 16 + fB]) = pw;
        }

        // ---- L3: 64 -> 124 (padded 128; h2 bf16-only, W3 split)
        f32x4 acc3[8];
        #pragma unroll
        for (int tile = 0; tile < 8; ++tile)
            acc3[tile] = *reinterpret_cast<const f32x4*>(&biasf[128 + tile * 16 + fB]);
        #pragma unroll
        for (int ks = 0; ks < 2; ++ks) {
            const bf16x8 hf = *reinterpret_cast<const bf16x8*>(&hh[col16 * 72 + ks * 32 + g * 8]);
            #pragma unroll
            for (int tile = 0; tile < 8; ++tile) {
                const int fo = 6144 + (ks * 8 + tile) * 512 + ln * 8;
                const bf16x8 wh = *reinterpret_cast<const bf16x8*>(&s_w[fo]);
                const bf16x8 wl = *reinterpret_cast<const bf16x8*>(&s_w[14336 + fo]);
                acc3[tile] = MFMA16(wl, hf, acc3[tile]);
                acc3[tile] = MFMA16(wh, hf, acc3[tile]);
            }
        }

        __syncthreads();   // all waves done reading s_w

        // ---- issue next block's weight staging (overlaps o-transpose + spline)
        if (blk < NBLK - 1) {
            const unsigned short* gsrc = WSF + (blk + 1) * 32768;
            #pragma unroll
            for (int r = 0; r < 7; ++r) {
                const int off = (r * 8 + wv) * 512;
                __builtin_amdgcn_global_load_lds(
                    (const __attribute__((address_space(1))) unsigned int*)(gsrc + off + ln * 8),
                    (__attribute__((address_space(3))) unsigned int*)(&s_w[off]),
                    16, 0, 0);
            }
            if (wv == 0) {
                const int off = 56 * 512;
                __builtin_amdgcn_global_load_lds(
                    (const __attribute__((address_space(1))) unsigned int*)(gsrc + off + ln * 8),
                    (__attribute__((address_space(3))) unsigned int*)(&s_w[off]),
                    16, 0, 0);
            }
        }

        // ---- o transpose: lane writes its 4 consecutive features per tile (b128)
        #pragma unroll
        for (int tile = 0; tile < 8; ++tile)
            *reinterpret_cast<f32x4*>(&op[col16 * 132 + tile * 16 + fB]) = acc3[tile];

        // ---- spline: lane = (sample col16, trafo slot g)
        float xt[4];
        #pragma unroll
        for (int j = 0; j < 4; ++j) {
            const int td = ((j >> p) << (p + 1)) | (tb << p) | (j & lm);
            xt[j] = s_x[srow * 8 + td];
        }
        const bool inside =
            (xt[0] >= 0.f) && (xt[0] <= 1.f) && (xt[1] >= 0.f) && (xt[1] <= 1.f) &&
            (xt[2] >= 0.f) && (xt[2] <= 1.f) && (xt[3] >= 0.f) && (xt[3] <= 1.f);
        float xtv = (g == 1) ? xt[1] : xt[0];
        xtv = (g == 2) ? xt[2] : xtv;
        xtv = (g == 3) ? xt[3] : xtv;
        const int ti = ((g >> p) << (p + 1)) | (tb << p) | (g & lm);

        float ov[31];
        {
            const float* ob = op + col16 * 132 + g * 31;
            #pragma unroll
            for (int j = 0; j < 31; ++j) ov[j] = ob[j];
        }

        // widths
        float mw = ov[0];
        #pragma unroll
        for (int k = 1; k < 10; ++k) mw = fmaxf(mw, ov[k]);
        float ew[10], sw = 0.f;
        #pragma unroll
        for (int k = 0; k < 10; ++k) { ew[k] = __expf(ov[k] - mw); sw += ew[k]; }
        const float fw = 0.99f / sw;
        float Cw[11];
        Cw[0] = 0.f;
        #pragma unroll
        for (int k = 1; k <= 10; ++k) Cw[k] = Cw[k - 1] + (0.001f + ew[k - 1] * fw);
        Cw[10] = 1.0f;
        float Wd[10];
        #pragma unroll
        for (int k = 0; k < 10; ++k) Wd[k] = Cw[k + 1] - Cw[k];

        // heights
        float mh = ov[10];
        #pragma unroll
        for (int k = 1; k < 10; ++k) mh = fmaxf(mh, ov[10 + k]);
        float eh[10], sh = 0.f;
        #pragma unroll
        for (int k = 0; k < 10; ++k) { eh[k] = __expf(ov[10 + k] - mh); sh += eh[k]; }
        const float fh = 0.99f / sh;
        float Ch[11];
        Ch[0] = 0.f;
        #pragma unroll
        for (int k = 1; k <= 10; ++k) Ch[k] = Ch[k - 1] + (0.001f + eh[k - 1] * fh);
        Ch[10] = 1.0f;
        float Hh[10];
        #pragma unroll
        for (int k = 0; k < 10; ++k) Hh[k] = Ch[k + 1] - Ch[k];

        // derivatives
        float dv[11];
        #pragma unroll
        for (int k = 0; k < 11; ++k) {
            const float u = ov[20 + k];
            const float sp = (u > 15.f) ? u : __logf(1.f + __expf(u));
            dv[k] = (0.001f + sp) * DNORM;
        }

        // bin search + gathers via compare-select scan
        const float xin = fminf(fmaxf(xtv, 0.f), 1.f);
        float in_cw = 0.f, in_bw = Wd[0], in_ch = 0.f, in_h = Hh[0];
        float in_d = dv[0], in_dp1 = dv[1];
        #pragma unroll
        for (int k = 1; k < 10; ++k) {
            const bool ge = (xin >= Cw[k]);
            in_cw  = ge ? Cw[k]     : in_cw;
            in_bw  = ge ? Wd[k]     : in_bw;
            in_ch  = ge ? Ch[k]     : in_ch;
            in_h   = ge ? Hh[k]     : in_h;
            in_d   = ge ? dv[k]     : in_d;
            in_dp1 = ge ? dv[k + 1] : in_dp1;
        }

        const float th   = (xin - in_cw) / in_bw;
        const float tomt = th * (1.f - th);
        const float dl   = in_h / in_bw;
        const float nume = in_h * (dl * th * th + in_d * tomt);
        const float deno = dl + (in_d + in_dp1 - 2.f * dl) * tomt;
        const float xout = in_ch + nume / deno;
        const float omt  = 1.f - th;
        const float dnum = dl * dl * (in_dp1 * th * th + 2.f * dl * tomt + in_d * omt * omt);
        const float lad  = __logf(dnum) - 2.f * __logf(deno);

        jacl += inside ? lad : 0.f;
        s_x[srow * 8 + ti] = inside ? xout : xtv;
    }

    // jac = sum over the 4 trafo-slot lanes of each sample
    jacl += __shfl_xor(jacl, 16);
    jacl += __shfl_xor(jacl, 32);
    if (ln < 16)
        JAC[(size_t)blockIdx.x * 128 + wv * 16 + ln] = jacl;
}

extern "C" void kernel_launch(void* const* d_in, const int* in_sizes, int n_in,
                              void* d_out, int out_size, void* d_ws, size_t ws_size,
                              hipStream_t stream) {
    (void)n_in; (void)ws_size;
    const float* X  = (const float*)d_in[0];
    const float* C4 = (const float*)d_in[1];
    const float* W1 = (const float*)d_in[2];
    const float* B1 = (const float*)d_in[3];
    const float* W2 = (const float*)d_in[4];
    const float* B2 = (const float*)d_in[5];
    const float* W3 = (const float*)d_in[6];
    const float* B3 = (const float*)d_in[7];
    float* out = (float*)d_out;
    unsigned short* wsf = (unsigned short*)d_ws;   // 6 * 32768 u16 = 384 KB

    hipLaunchKernelGGL(prep_kernel, dim3(NBLK), dim3(1024), 0, stream,
                       W1, B1, W2, B2, W3, B3, wsf);

    const int n = in_sizes[0] / 8;                 // 262144
    hipLaunchKernelGGL(flow_kernel, dim3(n / 128), dim3(TPB), 0, stream,
                       X, C4, wsf, out);
}

// Round 10
// 270.103 us; speedup vs baseline: 10.4784x; 1.0231x over previous
//
#include <hip/hip_runtime.h>
#include <math.h>

#define TPB 768
#define WGS 192              // samples per workgroup (12 waves x 16)
#define NBLK 6
#define DNORM (1.0f / (0.001f + 0.69314718055994530942f))

typedef float  f32x4  __attribute__((ext_vector_type(4)));
typedef short  bf16x8 __attribute__((ext_vector_type(8)));

#define MFMA16(A, B, C) __builtin_amdgcn_mfma_f32_16x16x32_bf16((A), (B), (C), 0, 0, 0)

// d_ws per-flow-block region: stride 32768 u16 = 64KB (content 29184 u16)
//   hi fragments : u16 [0 .. 14335]     (w1f 2048 | w2f 4096 | w3f 8192)
//   lo fragments : u16 [14336 .. 28671] (same structure)
//   bias         : f32 [256] at u16 offset 28672 (b1 64 | b2 64 | b3p 128)
// UNPERMUTED layout (round-7 proven): position 16*tile + (lane&15) = real col.

__device__ __forceinline__ float leaky(float a) { return a >= 0.f ? a : 0.01f * a; }

__device__ __forceinline__ unsigned int bfbits(float f) {
    unsigned int u = __float_as_uint(f);
    return (u + 0x7fffu + ((u >> 16) & 1u)) >> 16;   // RNE to bf16
}
__device__ __forceinline__ float bf2f(unsigned int h) {
    return __uint_as_float(h << 16);
}
__device__ __forceinline__ unsigned int pk2(float a, float b) {
    return bfbits(a) | (bfbits(b) << 16);
}

__global__ void prep_kernel(const float* __restrict__ W1, const float* __restrict__ B1,
                            const float* __restrict__ W2, const float* __restrict__ B2,
                            const float* __restrict__ W3, const float* __restrict__ B3,
                            unsigned short* __restrict__ wsf)
{
    const int blk = blockIdx.x;
    const int tid = threadIdx.x;          // 1024 threads
    unsigned short* base = wsf + blk * 32768;
    const float* w1 = W1 + blk * 512;
    const float* w2 = W2 + blk * 4096;
    const float* w3 = W3 + blk * 7936;

    for (int e = tid; e < 2048; e += 1024) {
        const int tile = e >> 9, lane = (e >> 3) & 63, i = e & 7;
        const int k = (lane >> 4) * 8 + i, col = tile * 16 + (lane & 15);
        const float f = (k < 8) ? w1[k * 64 + col] : 0.f;
        const unsigned int uh = bfbits(f);
        base[e]         = (unsigned short)uh;
        base[14336 + e] = (unsigned short)bfbits(f - bf2f(uh));
    }
    for (int e = tid; e < 4096; e += 1024) {
        const int ks = e >> 11, tile = (e >> 9) & 3, lane = (e >> 3) & 63, i = e & 7;
        const int k = ks * 32 + (lane >> 4) * 8 + i, col = tile * 16 + (lane & 15);
        const float f = w2[k * 64 + col];
        const unsigned int uh = bfbits(f);
        base[2048 + e]         = (unsigned short)uh;
        base[14336 + 2048 + e] = (unsigned short)bfbits(f - bf2f(uh));
    }
    for (int e = tid; e < 8192; e += 1024) {
        const int ks = e >> 12, tile = (e >> 9) & 7, lane = (e >> 3) & 63, i = e & 7;
        const int k = ks * 32 + (lane >> 4) * 8 + i, col = tile * 16 + (lane & 15);
        const float f = (col < 124) ? w3[k * 124 + col] : 0.f;
        const unsigned int uh = bfbits(f);
        base[6144 + e]         = (unsigned short)uh;
        base[14336 + 6144 + e] = (unsigned short)bfbits(f - bf2f(uh));
    }
    float* bb = reinterpret_cast<float*>(base + 28672);
    if (tid < 64) { bb[tid] = B1[blk * 64 + tid]; bb[64 + tid] = B2[blk * 64 + tid]; }
    if (tid >= 128 && tid < 256) {
        const int j = tid - 128;
        bb[128 + j] = (j < 124) ? B3[blk * 124 + j] : 0.f;
    }
}

__global__ __launch_bounds__(TPB, 2) void flow_kernel(
    const float* __restrict__ X, const float* __restrict__ C4,
    const unsigned short* __restrict__ WSF, float* __restrict__ JAC, int n)
{
    // 159,744 B static LDS -> 1 WG/CU, 12 waves/CU = 3 waves/SIMD
    __shared__ __align__(16) unsigned short s_w[29184];   // 57KB: hi | lo | bias(f32)
    __shared__ __align__(16) unsigned char  s_u[95232];   // 12 waves x 7936B: union{ h[16][72] bf16, o[16][124] f32 }
    __shared__ __align__(16) float          s_x[1536];    // [192][8] f32 exact x state

    const int tid   = threadIdx.x;
    const int wv    = tid >> 6;        // 0..11
    const int ln    = tid & 63;
    const int col16 = ln & 15;         // MFMA col = SAMPLE slot
    const int g     = ln >> 4;         // k-group / feature-row group / trafo slot
    const int srow  = wv * 16 + col16; // this lane's sample row (0..191)
    const int wgBase = blockIdx.x * WGS;

    unsigned short* hh = reinterpret_cast<unsigned short*>(s_u + wv * 7936); // [16][72] bf16
    float*          op = reinterpret_cast<float*>(s_u + wv * 7936);          // [16][124] f32 (overlays hh)

    // ---- initial x load -> LDS (tail-guarded); c stays in registers
    {
        const int smp = wgBase + (tid >> 2);
        float2 xv = make_float2(0.5f, 0.5f);
        if (smp < n)
            xv = reinterpret_cast<const float2*>(X)[(size_t)blockIdx.x * (WGS * 4) + tid];
        reinterpret_cast<float2*>(s_x)[tid] = xv;
    }
    float4 cvv = make_float4(0.f, 0.f, 0.f, 0.f);
    if (wgBase + srow < n)
        cvv = reinterpret_cast<const float4*>(C4)[(size_t)wgBase + srow];

    // ---- stage block 0 weights (57 chunks x 1024B over 12 waves)
    {
        const unsigned short* gsrc = WSF;
        #pragma unroll
        for (int r = 0; r < 5; ++r) {
            const int ch = r * 12 + wv;
            if (ch < 57) {
                const int off = ch * 512;   // u16 units, wave-uniform
                __builtin_amdgcn_global_load_lds(
                    (const __attribute__((address_space(1))) unsigned int*)(gsrc + off + ln * 8),
                    (__attribute__((address_space(3))) unsigned int*)(&s_w[off]),
                    16, 0, 0);
            }
        }
    }

    const float* biasf = reinterpret_cast<const float*>(&s_w[28672]);
    const int fB = g * 4;              // this lane's feature offset within a 16-row tile
    float jacl = 0.f;

    #pragma unroll 1
    for (int blk = 0; blk < NBLK; ++blk) {
        __syncthreads();   // staged weights visible; per-wave scratch free

        const int p  = blk >> 1;
        const int cb = (blk & 1) ^ 1;
        const int tb = blk & 1;
        const int lm = (1 << p) - 1;

        // ---- conditioning inputs: x[cond dims] ++ c, hi/lo split (B-operand, k<8 => g==0)
        float xcf[8];
        #pragma unroll
        for (int j = 0; j < 4; ++j) {
            const int cd = ((j >> p) << (p + 1)) | (cb << p) | (j & lm);
            xcf[j] = s_x[srow * 8 + cd];
        }
        xcf[4] = cvv.x; xcf[5] = cvv.y; xcf[6] = cvv.z; xcf[7] = cvv.w;

        union { unsigned int u[4]; bf16x8 v; } bxh, bxl;
        #pragma unroll
        for (int q = 0; q < 4; ++q) {
            const unsigned int h0 = bfbits(xcf[2 * q]);
            const unsigned int l0 = bfbits(xcf[2 * q] - bf2f(h0));
            const unsigned int h1 = bfbits(xcf[2 * q + 1]);
            const unsigned int l1 = bfbits(xcf[2 * q + 1] - bf2f(h1));
            bxh.u[q] = (g == 0) ? (h0 | (h1 << 16)) : 0u;
            bxl.u[q] = (g == 0) ? (l0 | (l1 << 16)) : 0u;
        }

        // ---- L1: D^T = W1^T(16f x 32k) * x(32k x 16s)
        #pragma unroll
        for (int tile = 0; tile < 4; ++tile) {
            f32x4 a1 = *reinterpret_cast<const f32x4*>(&biasf[tile * 16 + fB]);
            const bf16x8 wh = *reinterpret_cast<const bf16x8*>(&s_w[tile * 512 + ln * 8]);
            const bf16x8 wl = *reinterpret_cast<const bf16x8*>(&s_w[14336 + tile * 512 + ln * 8]);
            a1 = MFMA16(wl, bxh.v, a1);
            a1 = MFMA16(wh, bxl.v, a1);
            a1 = MFMA16(wh, bxh.v, a1);
            uint2 pw;
            pw.x = pk2(leaky(a1[0]), leaky(a1[1]));
            pw.y = pk2(leaky(a1[2]), leaky(a1[3]));
            *reinterpret_cast<uint2*>(&hh[col16 * 72 + tile * 16 + fB]) = pw;  // ds_write_b64
        }

        // ---- L2: 64 -> 64 (h1 bf16-only; W2 split)
        f32x4 acc2[4];
        #pragma unroll
        for (int tile = 0; tile < 4; ++tile)
            acc2[tile] = *reinterpret_cast<const f32x4*>(&biasf[64 + tile * 16 + fB]);
        #pragma unroll
        for (int ks = 0; ks < 2; ++ks) {
            const bf16x8 hf = *reinterpret_cast<const bf16x8*>(&hh[col16 * 72 + ks * 32 + g * 8]);
            #pragma unroll
            for (int tile = 0; tile < 4; ++tile) {
                const int fo = 2048 + (ks * 4 + tile) * 512 + ln * 8;
                const bf16x8 wh = *reinterpret_cast<const bf16x8*>(&s_w[fo]);
                const bf16x8 wl = *reinterpret_cast<const bf16x8*>(&s_w[14336 + fo]);
                acc2[tile] = MFMA16(wl, hf, acc2[tile]);
                acc2[tile] = MFMA16(wh, hf, acc2[tile]);
            }
        }
        #pragma unroll
        for (int tile = 0; tile < 4; ++tile) {
            uint2 pw;
            pw.x = pk2(leaky(acc2[tile][0]), leaky(acc2[tile][1]));
            pw.y = pk2(leaky(acc2[tile][2]), leaky(acc2[tile][3]));
            *reinterpret_cast<uint2*>(&hh[col16 * 72 + tile * 16 + fB]) = pw;
        }

        // ---- L3: 64 -> 124 (padded 128; h2 bf16-only, W3 split)
        f32x4 acc3[8];
        #pragma unroll
        for (int tile = 0; tile < 8; ++tile)
            acc3[tile] = *reinterpret_cast<const f32x4*>(&biasf[128 + tile * 16 + fB]);
        #pragma unroll
        for (int ks = 0; ks < 2; ++ks) {
            const bf16x8 hf = *reinterpret_cast<const bf16x8*>(&hh[col16 * 72 + ks * 32 + g * 8]);
            #pragma unroll
            for (int tile = 0; tile < 8; ++tile) {
                const int fo = 6144 + (ks * 8 + tile) * 512 + ln * 8;
                const bf16x8 wh = *reinterpret_cast<const bf16x8*>(&s_w[fo]);
                const bf16x8 wl = *reinterpret_cast<const bf16x8*>(&s_w[14336 + fo]);
                acc3[tile] = MFMA16(wl, hf, acc3[tile]);
                acc3[tile] = MFMA16(wh, hf, acc3[tile]);
            }
        }

        __syncthreads();   // all waves done reading s_w

        // ---- issue next block's weight staging (overlaps o-transpose + spline)
        if (blk < NBLK - 1) {
            const unsigned short* gsrc = WSF + (blk + 1) * 32768;
            #pragma unroll
            for (int r = 0; r < 5; ++r) {
                const int ch = r * 12 + wv;
                if (ch < 57) {
                    const int off = ch * 512;
                    __builtin_amdgcn_global_load_lds(
                        (const __attribute__((address_space(1))) unsigned int*)(gsrc + off + ln * 8),
                        (__attribute__((address_space(3))) unsigned int*)(&s_w[off]),
                        16, 0, 0);
                }
            }
        }

        // ---- o transpose: lane writes its 4 consecutive features per tile (b128)
        #pragma unroll
        for (int tile = 0; tile < 8; ++tile)
            if (tile * 16 + fB < 124)
                *reinterpret_cast<f32x4*>(&op[col16 * 124 + tile * 16 + fB]) = acc3[tile];

        // ---- spline: lane = (sample col16, trafo slot g)
        float xt[4];
        #pragma unroll
        for (int j = 0; j < 4; ++j) {
            const int td = ((j >> p) << (p + 1)) | (tb << p) | (j & lm);
            xt[j] = s_x[srow * 8 + td];
        }
        const bool inside =
            (xt[0] >= 0.f) && (xt[0] <= 1.f) && (xt[1] >= 0.f) && (xt[1] <= 1.f) &&
            (xt[2] >= 0.f) && (xt[2] <= 1.f) && (xt[3] >= 0.f) && (xt[3] <= 1.f);
        float xtv = (g == 1) ? xt[1] : xt[0];
        xtv = (g == 2) ? xt[2] : xtv;
        xtv = (g == 3) ? xt[3] : xtv;
        const int ti = ((g >> p) << (p + 1)) | (tb << p) | (g & lm);

        float ov[31];
        {
            const float* ob = op + col16 * 124 + g * 31;
            #pragma unroll
            for (int j = 0; j < 31; ++j) ov[j] = ob[j];
        }

        // widths
        float mw = ov[0];
        #pragma unroll
        for (int k = 1; k < 10; ++k) mw = fmaxf(mw, ov[k]);
        float ew[10], sw = 0.f;
        #pragma unroll
        for (int k = 0; k < 10; ++k) { ew[k] = __expf(ov[k] - mw); sw += ew[k]; }
        const float fw = 0.99f / sw;
        float Cw[11];
        Cw[0] = 0.f;
        #pragma unroll
        for (int k = 1; k <= 10; ++k) Cw[k] = Cw[k - 1] + (0.001f + ew[k - 1] * fw);
        Cw[10] = 1.0f;
        float Wd[10];
        #pragma unroll
        for (int k = 0; k < 10; ++k) Wd[k] = Cw[k + 1] - Cw[k];

        // heights
        float mh = ov[10];
        #pragma unroll
        for (int k = 1; k < 10; ++k) mh = fmaxf(mh, ov[10 + k]);
        float eh[10], sh = 0.f;
        #pragma unroll
        for (int k = 0; k < 10; ++k) { eh[k] = __expf(ov[10 + k] - mh); sh += eh[k]; }
        const float fh = 0.99f / sh;
        float Ch[11];
        Ch[0] = 0.f;
        #pragma unroll
        for (int k = 1; k <= 10; ++k) Ch[k] = Ch[k - 1] + (0.001f + eh[k - 1] * fh);
        Ch[10] = 1.0f;
        float Hh[10];
        #pragma unroll
        for (int k = 0; k < 10; ++k) Hh[k] = Ch[k + 1] - Ch[k];

        // derivatives
        float dv[11];
        #pragma unroll
        for (int k = 0; k < 11; ++k) {
            const float u = ov[20 + k];
            const float sp = (u > 15.f) ? u : __logf(1.f + __expf(u));
            dv[k] = (0.001f + sp) * DNORM;
        }

        // bin search + gathers via compare-select scan
        const float xin = fminf(fmaxf(xtv, 0.f), 1.f);
        float in_cw = 0.f, in_bw = Wd[0], in_ch = 0.f, in_h = Hh[0];
        float in_d = dv[0], in_dp1 = dv[1];
        #pragma unroll
        for (int k = 1; k < 10; ++k) {
            const bool ge = (xin >= Cw[k]);
            in_cw  = ge ? Cw[k]     : in_cw;
            in_bw  = ge ? Wd[k]     : in_bw;
            in_ch  = ge ? Ch[k]     : in_ch;
            in_h   = ge ? Hh[k]     : in_h;
            in_d   = ge ? dv[k]     : in_d;
            in_dp1 = ge ? dv[k + 1] : in_dp1;
        }

        const float th   = (xin - in_cw) / in_bw;
        const float tomt = th * (1.f - th);
        const float dl   = in_h / in_bw;
        const float nume = in_h * (dl * th * th + in_d * tomt);
        const float deno = dl + (in_d + in_dp1 - 2.f * dl) * tomt;
        const float xout = in_ch + nume / deno;
        const float omt  = 1.f - th;
        const float dnum = dl * dl * (in_dp1 * th * th + 2.f * dl * tomt + in_d * omt * omt);
        const float lad  = __logf(dnum) - 2.f * __logf(deno);

        jacl += inside ? lad : 0.f;
        s_x[srow * 8 + ti] = inside ? xout : xtv;
    }

    // jac = sum over the 4 trafo-slot lanes of each sample
    jacl += __shfl_xor(jacl, 16);
    jacl += __shfl_xor(jacl, 32);
    if (ln < 16) {
        const int smp = wgBase + wv * 16 + ln;
        if (smp < n) JAC[smp] = jacl;
    }
}

extern "C" void kernel_launch(void* const* d_in, const int* in_sizes, int n_in,
                              void* d_out, int out_size, void* d_ws, size_t ws_size,
                              hipStream_t stream) {
    (void)n_in; (void)ws_size;
    const float* X  = (const float*)d_in[0];
    const float* C4 = (const float*)d_in[1];
    const float* W1 = (const float*)d_in[2];
    const float* B1 = (const float*)d_in[3];
    const float* W2 = (const float*)d_in[4];
    const float* B2 = (const float*)d_in[5];
    const float* W3 = (const float*)d_in[6];
    const float* B3 = (const float*)d_in[7];
    float* out = (float*)d_out;
    unsigned short* wsf = (unsigned short*)d_ws;   // 6 * 32768 u16 = 384 KB

    hipLaunchKernelGGL(prep_kernel, dim3(NBLK), dim3(1024), 0, stream,
                       W1, B1, W2, B2, W3, B3, wsf);

    const int n = in_sizes[0] / 8;                 // 262144
    const int grid = (n + WGS - 1) / WGS;          // 1366
    hipLaunchKernelGGL(flow_kernel, dim3(grid), dim3(TPB), 0, stream,
                       X, C4, wsf, out, n);
}

// Round 11
// 245.366 us; speedup vs baseline: 11.5348x; 1.1008x over previous
//
#include <hip/hip_runtime.h>
#include <math.h>

#define TPB 960
#define WGS 240              // samples per workgroup (15 waves x 16)
#define NBLK 6
#define SW_U16 16896         // staged weights+bias content (u16 units)
#define CHUNKS 33            // SW_U16 / 512
#define DNORM (1.0f / (0.001f + 0.69314718055994530942f))

typedef float  f32x4  __attribute__((ext_vector_type(4)));
typedef short  bf16x8 __attribute__((ext_vector_type(8)));

#define MFMA16(A, B, C) __builtin_amdgcn_mfma_f32_16x16x32_bf16((A), (B), (C), 0, 0, 0)

// d_ws per-flow-block region: stride 32768 u16 = 64KB (content 16896 u16)
//   W1 hi : u16 [0 .. 2047]      (4 frags x 512; K=8 zero-padded)
//   W1 lo : u16 [2048 .. 4095]   (split kept -> exact x conditioning)
//   W2 hi : u16 [4096 .. 8191]   (8 frags; bf16-only)
//   W3 hi : u16 [8192 .. 16383]  (16 frags; bf16-only, col>=124 zeroed)
//   bias  : f32 [256] at u16 16384 (b1 64 | b2 64 | b3p 128)
// UNPERMUTED (round-7 proven): fragment position 16*tile + (lane&15) = real col.

__device__ __forceinline__ float leaky(float a) { return a >= 0.f ? a : 0.01f * a; }

__device__ __forceinline__ unsigned int bfbits(float f) {
    unsigned int u = __float_as_uint(f);
    return (u + 0x7fffu + ((u >> 16) & 1u)) >> 16;   // RNE to bf16
}
__device__ __forceinline__ float bf2f(unsigned int h) {
    return __uint_as_float(h << 16);
}
__device__ __forceinline__ unsigned int pk2(float a, float b) {
    return bfbits(a) | (bfbits(b) << 16);
}

__global__ void prep_kernel(const float* __restrict__ W1, const float* __restrict__ B1,
                            const float* __restrict__ W2, const float* __restrict__ B2,
                            const float* __restrict__ W3, const float* __restrict__ B3,
                            unsigned short* __restrict__ wsf)
{
    const int blk = blockIdx.x;
    const int tid = threadIdx.x;          // 1024 threads
    unsigned short* base = wsf + blk * 32768;
    const float* w1 = W1 + blk * 512;
    const float* w2 = W2 + blk * 4096;
    const float* w3 = W3 + blk * 7936;

    for (int e = tid; e < 2048; e += 1024) {
        const int tile = e >> 9, lane = (e >> 3) & 63, i = e & 7;
        const int k = (lane >> 4) * 8 + i, col = tile * 16 + (lane & 15);
        const float f = (k < 8) ? w1[k * 64 + col] : 0.f;
        const unsigned int uh = bfbits(f);
        base[e]        = (unsigned short)uh;
        base[2048 + e] = (unsigned short)bfbits(f - bf2f(uh));   // W1 lo
    }
    for (int e = tid; e < 4096; e += 1024) {
        const int ks = e >> 11, tile = (e >> 9) & 3, lane = (e >> 3) & 63, i = e & 7;
        const int k = ks * 32 + (lane >> 4) * 8 + i, col = tile * 16 + (lane & 15);
        base[4096 + e] = (unsigned short)bfbits(w2[k * 64 + col]);   // W2 hi only
    }
    for (int e = tid; e < 8192; e += 1024) {
        const int ks = e >> 12, tile = (e >> 9) & 7, lane = (e >> 3) & 63, i = e & 7;
        const int k = ks * 32 + (lane >> 4) * 8 + i, col = tile * 16 + (lane & 15);
        const float f = (col < 124) ? w3[k * 124 + col] : 0.f;
        base[8192 + e] = (unsigned short)bfbits(f);                  // W3 hi only
    }
    float* bb = reinterpret_cast<float*>(base + 16384);
    if (tid < 64) { bb[tid] = B1[blk * 64 + tid]; bb[64 + tid] = B2[blk * 64 + tid]; }
    if (tid >= 128 && tid < 256) {
        const int j = tid - 128;
        bb[128 + j] = (j < 124) ? B3[blk * 124 + j] : 0.f;
    }
}

__global__ __launch_bounds__(TPB, 4) void flow_kernel(
    const float* __restrict__ X, const float* __restrict__ C4,
    const unsigned short* __restrict__ WSF, float* __restrict__ JAC, int n)
{
    // 161,472 B static LDS -> 1 WG/CU, 15 waves/CU
    __shared__ __align__(16) unsigned short s_w[SW_U16];  // 33KB: W1 hi|lo, W2 hi, W3 hi, bias(f32)
    __shared__ __align__(16) unsigned char  s_u[119040];  // 15 waves x 7936B: union{ h[16][72] bf16, o[16][124] f32 }
    __shared__ __align__(16) float          s_x[2160];    // [240][9] f32 (pad 9 -> conflict-free)

    const int tid   = threadIdx.x;
    const int wv    = tid >> 6;        // 0..14
    const int ln    = tid & 63;
    const int col16 = ln & 15;         // MFMA col = SAMPLE slot
    const int g     = ln >> 4;         // k-group / feature-row group / trafo slot
    const int srow  = wv * 16 + col16; // this lane's sample row (0..239)
    const int wgBase = blockIdx.x * WGS;

    unsigned short* hh = reinterpret_cast<unsigned short*>(s_u + wv * 7936); // [16][72] bf16
    float*          op = reinterpret_cast<float*>(s_u + wv * 7936);          // [16][124] f32 (overlays hh)

    // ---- initial x load -> LDS (stride-9, tail-guarded); c stays in registers
    {
        const int s   = tid >> 2;            // 0..239
        const int d0  = (tid & 3) * 2;
        const int smp = wgBase + s;
        float2 xv = make_float2(0.5f, 0.5f);
        if (smp < n)
            xv = reinterpret_cast<const float2*>(X)[(size_t)smp * 4 + (tid & 3)];
        s_x[s * 9 + d0]     = xv.x;
        s_x[s * 9 + d0 + 1] = xv.y;
    }
    float4 cvv = make_float4(0.f, 0.f, 0.f, 0.f);
    if (wgBase + srow < n)
        cvv = reinterpret_cast<const float4*>(C4)[(size_t)wgBase + srow];

    // ---- stage block 0 weights (33 chunks x 1024B over 15 waves)
    {
        const unsigned short* gsrc = WSF;
        #pragma unroll
        for (int r = 0; r < 3; ++r) {
            const int ch = r * 15 + wv;
            if (ch < CHUNKS) {
                const int off = ch * 512;   // u16 units, wave-uniform
                __builtin_amdgcn_global_load_lds(
                    (const __attribute__((address_space(1))) unsigned int*)(gsrc + off + ln * 8),
                    (__attribute__((address_space(3))) unsigned int*)(&s_w[off]),
                    16, 0, 0);
            }
        }
    }

    const float* biasf = reinterpret_cast<const float*>(&s_w[16384]);
    const int fB = g * 4;              // this lane's feature offset within a 16-row tile
    float jacl = 0.f;

    #pragma unroll 1
    for (int blk = 0; blk < NBLK; ++blk) {
        __syncthreads();   // staged weights visible; per-wave scratch free

        const int p  = blk >> 1;
        const int cb = (blk & 1) ^ 1;
        const int tb = blk & 1;
        const int lm = (1 << p) - 1;

        // ---- conditioning inputs: x[cond dims] ++ c, hi/lo split (B-operand, k<8 => g==0)
        float xcf[8];
        #pragma unroll
        for (int j = 0; j < 4; ++j) {
            const int cd = ((j >> p) << (p + 1)) | (cb << p) | (j & lm);
            xcf[j] = s_x[srow * 9 + cd];
        }
        xcf[4] = cvv.x; xcf[5] = cvv.y; xcf[6] = cvv.z; xcf[7] = cvv.w;

        union { unsigned int u[4]; bf16x8 v; } bxh, bxl;
        #pragma unroll
        for (int q = 0; q < 4; ++q) {
            const unsigned int h0 = bfbits(xcf[2 * q]);
            const unsigned int l0 = bfbits(xcf[2 * q] - bf2f(h0));
            const unsigned int h1 = bfbits(xcf[2 * q + 1]);
            const unsigned int l1 = bfbits(xcf[2 * q + 1] - bf2f(h1));
            bxh.u[q] = (g == 0) ? (h0 | (h1 << 16)) : 0u;
            bxl.u[q] = (g == 0) ? (l0 | (l1 << 16)) : 0u;
        }

        // ---- L1: D^T = W1^T(16f x 32k) * x(32k x 16s); W1 split, x split
        #pragma unroll
        for (int tile = 0; tile < 4; ++tile) {
            f32x4 a1 = *reinterpret_cast<const f32x4*>(&biasf[tile * 16 + fB]);
            const bf16x8 wh = *reinterpret_cast<const bf16x8*>(&s_w[tile * 512 + ln * 8]);
            const bf16x8 wl = *reinterpret_cast<const bf16x8*>(&s_w[2048 + tile * 512 + ln * 8]);
            a1 = MFMA16(wl, bxh.v, a1);
            a1 = MFMA16(wh, bxl.v, a1);
            a1 = MFMA16(wh, bxh.v, a1);
            uint2 pw;
            pw.x = pk2(leaky(a1[0]), leaky(a1[1]));
            pw.y = pk2(leaky(a1[2]), leaky(a1[3]));
            *reinterpret_cast<uint2*>(&hh[col16 * 72 + tile * 16 + fB]) = pw;  // ds_write_b64
        }

        // ---- L2: 64 -> 64 (h1 bf16, W2 bf16-only)
        f32x4 acc2[4];
        #pragma unroll
        for (int tile = 0; tile < 4; ++tile)
            acc2[tile] = *reinterpret_cast<const f32x4*>(&biasf[64 + tile * 16 + fB]);
        #pragma unroll
        for (int ks = 0; ks < 2; ++ks) {
            const bf16x8 hf = *reinterpret_cast<const bf16x8*>(&hh[col16 * 72 + ks * 32 + g * 8]);
            #pragma unroll
            for (int tile = 0; tile < 4; ++tile) {
                const bf16x8 wh = *reinterpret_cast<const bf16x8*>(
                    &s_w[4096 + (ks * 4 + tile) * 512 + ln * 8]);
                acc2[tile] = MFMA16(wh, hf, acc2[tile]);
            }
        }
        #pragma unroll
        for (int tile = 0; tile < 4; ++tile) {
            uint2 pw;
            pw.x = pk2(leaky(acc2[tile][0]), leaky(acc2[tile][1]));
            pw.y = pk2(leaky(acc2[tile][2]), leaky(acc2[tile][3]));
            *reinterpret_cast<uint2*>(&hh[col16 * 72 + tile * 16 + fB]) = pw;
        }

        // ---- L3: 64 -> 124 (padded 128; h2 bf16, W3 bf16-only)
        f32x4 acc3[8];
        #pragma unroll
        for (int tile = 0; tile < 8; ++tile)
            acc3[tile] = *reinterpret_cast<const f32x4*>(&biasf[128 + tile * 16 + fB]);
        #pragma unroll
        for (int ks = 0; ks < 2; ++ks) {
            const bf16x8 hf = *reinterpret_cast<const bf16x8*>(&hh[col16 * 72 + ks * 32 + g * 8]);
            #pragma unroll
            for (int tile = 0; tile < 8; ++tile) {
                const bf16x8 wh = *reinterpret_cast<const bf16x8*>(
                    &s_w[8192 + (ks * 8 + tile) * 512 + ln * 8]);
                acc3[tile] = MFMA16(wh, hf, acc3[tile]);
            }
        }

        __syncthreads();   // all waves done reading s_w

        // ---- issue next block's weight staging (overlaps o-transpose + spline)
        if (blk < NBLK - 1) {
            const unsigned short* gsrc = WSF + (blk + 1) * 32768;
            #pragma unroll
            for (int r = 0; r < 3; ++r) {
                const int ch = r * 15 + wv;
                if (ch < CHUNKS) {
                    const int off = ch * 512;
                    __builtin_amdgcn_global_load_lds(
                        (const __attribute__((address_space(1))) unsigned int*)(gsrc + off + ln * 8),
                        (__attribute__((address_space(3))) unsigned int*)(&s_w[off]),
                        16, 0, 0);
                }
            }
        }

        // ---- o transpose: lane writes its 4 consecutive features per tile (b128)
        #pragma unroll
        for (int tile = 0; tile < 8; ++tile)
            if (tile * 16 + fB < 124)
                *reinterpret_cast<f32x4*>(&op[col16 * 124 + tile * 16 + fB]) = acc3[tile];

        // ---- spline: lane = (sample col16, trafo slot g)
        float xt[4];
        #pragma unroll
        for (int j = 0; j < 4; ++j) {
            const int td = ((j >> p) << (p + 1)) | (tb << p) | (j & lm);
            xt[j] = s_x[srow * 9 + td];
        }
        const bool inside =
            (xt[0] >= 0.f) && (xt[0] <= 1.f) && (xt[1] >= 0.f) && (xt[1] <= 1.f) &&
            (xt[2] >= 0.f) && (xt[2] <= 1.f) && (xt[3] >= 0.f) && (xt[3] <= 1.f);
        float xtv = (g == 1) ? xt[1] : xt[0];
        xtv = (g == 2) ? xt[2] : xtv;
        xtv = (g == 3) ? xt[3] : xtv;
        const int ti = ((g >> p) << (p + 1)) | (tb << p) | (g & lm);

        float ov[31];
        {
            const float* ob = op + col16 * 124 + g * 31;
            #pragma unroll
            for (int j = 0; j < 31; ++j) ov[j] = ob[j];
        }

        // widths
        float mw = ov[0];
        #pragma unroll
        for (int k = 1; k < 10; ++k) mw = fmaxf(mw, ov[k]);
        float ew[10], sw = 0.f;
        #pragma unroll
        for (int k = 0; k < 10; ++k) { ew[k] = __expf(ov[k] - mw); sw += ew[k]; }
        const float fw = 0.99f / sw;
        float Cw[11];
        Cw[0] = 0.f;
        #pragma unroll
        for (int k = 1; k <= 10; ++k) Cw[k] = Cw[k - 1] + (0.001f + ew[k - 1] * fw);
        Cw[10] = 1.0f;
        float Wd[10];
        #pragma unroll
        for (int k = 0; k < 10; ++k) Wd[k] = Cw[k + 1] - Cw[k];

        // heights
        float mh = ov[10];
        #pragma unroll
        for (int k = 1; k < 10; ++k) mh = fmaxf(mh, ov[10 + k]);
        float eh[10], sh = 0.f;
        #pragma unroll
        for (int k = 0; k < 10; ++k) { eh[k] = __expf(ov[10 + k] - mh); sh += eh[k]; }
        const float fh = 0.99f / sh;
        float Ch[11];
        Ch[0] = 0.f;
        #pragma unroll
        for (int k = 1; k <= 10; ++k) Ch[k] = Ch[k - 1] + (0.001f + eh[k - 1] * fh);
        Ch[10] = 1.0f;
        float Hh[10];
        #pragma unroll
        for (int k = 0; k < 10; ++k) Hh[k] = Ch[k + 1] - Ch[k];

        // derivatives
        float dv[11];
        #pragma unroll
        for (int k = 0; k < 11; ++k) {
            const float u = ov[20 + k];
            const float sp = (u > 15.f) ? u : __logf(1.f + __expf(u));
            dv[k] = (0.001f + sp) * DNORM;
        }

        // bin search + gathers via compare-select scan
        const float xin = fminf(fmaxf(xtv, 0.f), 1.f);
        float in_cw = 0.f, in_bw = Wd[0], in_ch = 0.f, in_h = Hh[0];
        float in_d = dv[0], in_dp1 = dv[1];
        #pragma unroll
        for (int k = 1; k < 10; ++k) {
            const bool ge = (xin >= Cw[k]);
            in_cw  = ge ? Cw[k]     : in_cw;
            in_bw  = ge ? Wd[k]     : in_bw;
            in_ch  = ge ? Ch[k]     : in_ch;
            in_h   = ge ? Hh[k]     : in_h;
            in_d   = ge ? dv[k]     : in_d;
            in_dp1 = ge ? dv[k + 1] : in_dp1;
        }

        const float th   = (xin - in_cw) / in_bw;
        const float tomt = th * (1.f - th);
        const float dl   = in_h / in_bw;
        const float nume = in_h * (dl * th * th + in_d * tomt);
        const float deno = dl + (in_d + in_dp1 - 2.f * dl) * tomt;
        const float xout = in_ch + nume / deno;
        const float omt  = 1.f - th;
        const float dnum = dl * dl * (in_dp1 * th * th + 2.f * dl * tomt + in_d * omt * omt);
        const float lad  = __logf(dnum) - 2.f * __logf(deno);

        jacl += inside ? lad : 0.f;
        s_x[srow * 9 + ti] = inside ? xout : xtv;
    }

    // jac = sum over the 4 trafo-slot lanes of each sample
    jacl += __shfl_xor(jacl, 16);
    jacl += __shfl_xor(jacl, 32);
    if (ln < 16) {
        const int smp = wgBase + wv * 16 + ln;
        if (smp < n) JAC[smp] = jacl;
    }
}

extern "C" void kernel_launch(void* const* d_in, const int* in_sizes, int n_in,
                              void* d_out, int out_size, void* d_ws, size_t ws_size,
                              hipStream_t stream) {
    (void)n_in; (void)ws_size;
    const float* X  = (const float*)d_in[0];
    const float* C4 = (const float*)d_in[1];
    const float* W1 = (const float*)d_in[2];
    const float* B1 = (const float*)d_in[3];
    const float* W2 = (const float*)d_in[4];
    const float* B2 = (const float*)d_in[5];
    const float* W3 = (const float*)d_in[6];
    const float* B3 = (const float*)d_in[7];
    float* out = (float*)d_out;
    unsigned short* wsf = (unsigned short*)d_ws;   // 6 * 32768 u16 = 384 KB

    hipLaunchKernelGGL(prep_kernel, dim3(NBLK), dim3(1024), 0, stream,
                       W1, B1, W2, B2, W3, B3, wsf);

    const int n = in_sizes[0] / 8;                 // 262144
    const int grid = (n + WGS - 1) / WGS;          // 1093
    hipLaunchKernelGGL(flow_kernel, dim3(grid), dim3(TPB), 0, stream,
                       X, C4, wsf, out, n);
}

// Round 12
// 231.857 us; speedup vs baseline: 12.2069x; 1.0583x over previous
//
#include <hip/hip_runtime.h>
#include <hip/hip_bf16.h>
#include <math.h>

#define TPB 960
#define WGS 240              // samples per workgroup (15 waves x 16)
#define NBLK 6
#define SW_U16 14848         // staged weights+bias content (u16 units)
#define CHUNKS 29            // SW_U16 / 512
#define DNORM (1.0f / (0.001f + 0.69314718055994530942f))

typedef float  f32x4  __attribute__((ext_vector_type(4)));
typedef short  bf16x8 __attribute__((ext_vector_type(8)));

#define MFMA16(A, B, C) __builtin_amdgcn_mfma_f32_16x16x32_bf16((A), (B), (C), 0, 0, 0)

// d_ws per-flow-block region: stride 32768 u16 = 64KB (content 14848 u16)
//   W1 hi : u16 [0 .. 2047]      (4 frags x 512; K=8 zero-padded; bf16-only)
//   W2 hi : u16 [2048 .. 6143]   (8 frags; bf16-only)
//   W3 hi : u16 [6144 .. 14335]  (16 frags; bf16-only, col>=124 zeroed)
//   bias  : f32 [256] at u16 14336 (b1 64 | b2 64 | b3p 128)
// UNPERMUTED (round-7 proven): fragment position 16*tile + (lane&15) = real col.

__device__ __forceinline__ float leaky(float a) { return a >= 0.f ? a : 0.01f * a; }

__device__ __forceinline__ unsigned int bfbits(float f) {
    unsigned int u = __float_as_uint(f);
    return (u + 0x7fffu + ((u >> 16) & 1u)) >> 16;   // RNE to bf16 (prep only)
}

// packed bf16x2 via v_cvt_pk_bf16_f32 (RNE, matches bfbits)
__device__ __forceinline__ unsigned int pkcvt(float a, float b) {
    __hip_bfloat162 t = __float22bfloat162_rn(make_float2(a, b));
    union { __hip_bfloat162 b2; unsigned int u; } cv;
    cv.b2 = t;
    return cv.u;
}

__global__ void prep_kernel(const float* __restrict__ W1, const float* __restrict__ B1,
                            const float* __restrict__ W2, const float* __restrict__ B2,
                            const float* __restrict__ W3, const float* __restrict__ B3,
                            unsigned short* __restrict__ wsf)
{
    const int blk = blockIdx.x;
    const int tid = threadIdx.x;          // 1024 threads
    unsigned short* base = wsf + blk * 32768;
    const float* w1 = W1 + blk * 512;
    const float* w2 = W2 + blk * 4096;
    const float* w3 = W3 + blk * 7936;

    for (int e = tid; e < 2048; e += 1024) {
        const int tile = e >> 9, lane = (e >> 3) & 63, i = e & 7;
        const int k = (lane >> 4) * 8 + i, col = tile * 16 + (lane & 15);
        const float f = (k < 8) ? w1[k * 64 + col] : 0.f;
        base[e] = (unsigned short)bfbits(f);                         // W1 hi only
    }
    for (int e = tid; e < 4096; e += 1024) {
        const int ks = e >> 11, tile = (e >> 9) & 3, lane = (e >> 3) & 63, i = e & 7;
        const int k = ks * 32 + (lane >> 4) * 8 + i, col = tile * 16 + (lane & 15);
        base[2048 + e] = (unsigned short)bfbits(w2[k * 64 + col]);   // W2 hi only
    }
    for (int e = tid; e < 8192; e += 1024) {
        const int ks = e >> 12, tile = (e >> 9) & 7, lane = (e >> 3) & 63, i = e & 7;
        const int k = ks * 32 + (lane >> 4) * 8 + i, col = tile * 16 + (lane & 15);
        const float f = (col < 124) ? w3[k * 124 + col] : 0.f;
        base[6144 + e] = (unsigned short)bfbits(f);                  // W3 hi only
    }
    float* bb = reinterpret_cast<float*>(base + 14336);
    if (tid < 64) { bb[tid] = B1[blk * 64 + tid]; bb[64 + tid] = B2[blk * 64 + tid]; }
    if (tid >= 128 && tid < 256) {
        const int j = tid - 128;
        bb[128 + j] = (j < 124) ? B3[blk * 124 + j] : 0.f;
    }
}

__global__ __launch_bounds__(TPB, 4) void flow_kernel(
    const float* __restrict__ X, const float* __restrict__ C4,
    const unsigned short* __restrict__ WSF, float* __restrict__ JAC, int n)
{
    // 157,376 B static LDS -> 1 WG/CU, 15 waves/CU
    __shared__ __align__(16) unsigned short s_w[SW_U16];  // 29KB: W1|W2|W3 hi + bias(f32)
    __shared__ __align__(16) unsigned char  s_u[119040];  // 15 waves x 7936B: union{ h[16][72] bf16, o[16][124] f32 }
    __shared__ __align__(16) float          s_x[2160];    // [240][9] f32 (pad 9 -> conflict-free)

    const int tid   = threadIdx.x;
    const int wv    = tid >> 6;        // 0..14
    const int ln    = tid & 63;
    const int col16 = ln & 15;         // MFMA col = SAMPLE slot
    const int g     = ln >> 4;         // k-group / feature-row group / trafo slot
    const int srow  = wv * 16 + col16; // this lane's sample row (0..239)
    const int wgBase = blockIdx.x * WGS;

    unsigned short* hh = reinterpret_cast<unsigned short*>(s_u + wv * 7936); // [16][72] bf16
    float*          op = reinterpret_cast<float*>(s_u + wv * 7936);          // [16][124] f32 (overlays hh)

    // ---- initial x load -> LDS (stride-9, tail-guarded); c stays in registers
    {
        const int s   = tid >> 2;            // 0..239
        const int d0  = (tid & 3) * 2;
        const int smp = wgBase + s;
        float2 xv = make_float2(0.5f, 0.5f);
        if (smp < n)
            xv = reinterpret_cast<const float2*>(X)[(size_t)smp * 4 + (tid & 3)];
        s_x[s * 9 + d0]     = xv.x;
        s_x[s * 9 + d0 + 1] = xv.y;
    }
    float4 cvv = make_float4(0.f, 0.f, 0.f, 0.f);
    if (wgBase + srow < n)
        cvv = reinterpret_cast<const float4*>(C4)[(size_t)wgBase + srow];

    // ---- stage block 0 weights (29 chunks x 1024B over 15 waves)
    {
        const unsigned short* gsrc = WSF;
        #pragma unroll
        for (int r = 0; r < 2; ++r) {
            const int ch = r * 15 + wv;
            if (ch < CHUNKS) {
                const int off = ch * 512;   // u16 units, wave-uniform
                __builtin_amdgcn_global_load_lds(
                    (const __attribute__((address_space(1))) unsigned int*)(gsrc + off + ln * 8),
                    (__attribute__((address_space(3))) unsigned int*)(&s_w[off]),
                    16, 0, 0);
            }
        }
    }

    const float* biasf = reinterpret_cast<const float*>(&s_w[14336]);
    const int fB = g * 4;              // this lane's feature offset within a 16-row tile
    float jacl = 0.f;

    #pragma unroll 1
    for (int blk = 0; blk < NBLK; ++blk) {
        __syncthreads();   // staged weights visible; per-wave scratch free

        const int p  = blk >> 1;
        const int cb = (blk & 1) ^ 1;
        const int tb = blk & 1;
        const int lm = (1 << p) - 1;

        // ---- conditioning inputs: x[cond dims] ++ c, bf16 (B-operand, k<8 => g==0)
        float xcf[8];
        #pragma unroll
        for (int j = 0; j < 4; ++j) {
            const int cd = ((j >> p) << (p + 1)) | (cb << p) | (j & lm);
            xcf[j] = s_x[srow * 9 + cd];
        }
        xcf[4] = cvv.x; xcf[5] = cvv.y; xcf[6] = cvv.z; xcf[7] = cvv.w;

        union { unsigned int u[4]; bf16x8 v; } bxh;
        #pragma unroll
        for (int q = 0; q < 4; ++q)
            bxh.u[q] = (g == 0) ? pkcvt(xcf[2 * q], xcf[2 * q + 1]) : 0u;

        // ---- L1: D^T = W1^T(16f x 32k) * x(32k x 16s), bf16-only
        #pragma unroll
        for (int tile = 0; tile < 4; ++tile) {
            f32x4 a1 = *reinterpret_cast<const f32x4*>(&biasf[tile * 16 + fB]);
            const bf16x8 wh = *reinterpret_cast<const bf16x8*>(&s_w[tile * 512 + ln * 8]);
            a1 = MFMA16(wh, bxh.v, a1);
            uint2 pw;
            pw.x = pkcvt(leaky(a1[0]), leaky(a1[1]));
            pw.y = pkcvt(leaky(a1[2]), leaky(a1[3]));
            *reinterpret_cast<uint2*>(&hh[col16 * 72 + tile * 16 + fB]) = pw;  // ds_write_b64
        }

        // ---- L2: 64 -> 64 (h1 bf16, W2 bf16-only)
        f32x4 acc2[4];
        #pragma unroll
        for (int tile = 0; tile < 4; ++tile)
            acc2[tile] = *reinterpret_cast<const f32x4*>(&biasf[64 + tile * 16 + fB]);
        #pragma unroll
        for (int ks = 0; ks < 2; ++ks) {
            const bf16x8 hf = *reinterpret_cast<const bf16x8*>(&hh[col16 * 72 + ks * 32 + g * 8]);
            #pragma unroll
            for (int tile = 0; tile < 4; ++tile) {
                const bf16x8 wh = *reinterpret_cast<const bf16x8*>(
                    &s_w[2048 + (ks * 4 + tile) * 512 + ln * 8]);
                acc2[tile] = MFMA16(wh, hf, acc2[tile]);
            }
        }
        #pragma unroll
        for (int tile = 0; tile < 4; ++tile) {
            uint2 pw;
            pw.x = pkcvt(leaky(acc2[tile][0]), leaky(acc2[tile][1]));
            pw.y = pkcvt(leaky(acc2[tile][2]), leaky(acc2[tile][3]));
            *reinterpret_cast<uint2*>(&hh[col16 * 72 + tile * 16 + fB]) = pw;
        }

        // ---- L3: 64 -> 124 (padded 128; h2 bf16, W3 bf16-only)
        f32x4 acc3[8];
        #pragma unroll
        for (int tile = 0; tile < 8; ++tile)
            acc3[tile] = *reinterpret_cast<const f32x4*>(&biasf[128 + tile * 16 + fB]);
        #pragma unroll
        for (int ks = 0; ks < 2; ++ks) {
            const bf16x8 hf = *reinterpret_cast<const bf16x8*>(&hh[col16 * 72 + ks * 32 + g * 8]);
            #pragma unroll
            for (int tile = 0; tile < 8; ++tile) {
                const bf16x8 wh = *reinterpret_cast<const bf16x8*>(
                    &s_w[6144 + (ks * 8 + tile) * 512 + ln * 8]);
                acc3[tile] = MFMA16(wh, hf, acc3[tile]);
            }
        }

        __syncthreads();   // all waves done reading s_w

        // ---- issue next block's weight staging (overlaps o-transpose + spline)
        if (blk < NBLK - 1) {
            const unsigned short* gsrc = WSF + (blk + 1) * 32768;
            #pragma unroll
            for (int r = 0; r < 2; ++r) {
                const int ch = r * 15 + wv;
                if (ch < CHUNKS) {
                    const int off = ch * 512;
                    __builtin_amdgcn_global_load_lds(
                        (const __attribute__((address_space(1))) unsigned int*)(gsrc + off + ln * 8),
                        (__attribute__((address_space(3))) unsigned int*)(&s_w[off]),
                        16, 0, 0);
                }
            }
        }

        // ---- o transpose: lane writes its 4 consecutive features per tile (b128)
        #pragma unroll
        for (int tile = 0; tile < 8; ++tile)
            if (tile * 16 + fB < 124)
                *reinterpret_cast<f32x4*>(&op[col16 * 124 + tile * 16 + fB]) = acc3[tile];

        // ---- spline: lane = (sample col16, trafo slot g)
        float xt[4];
        #pragma unroll
        for (int j = 0; j < 4; ++j) {
            const int td = ((j >> p) << (p + 1)) | (tb << p) | (j & lm);
            xt[j] = s_x[srow * 9 + td];
        }
        const bool inside =
            (xt[0] >= 0.f) && (xt[0] <= 1.f) && (xt[1] >= 0.f) && (xt[1] <= 1.f) &&
            (xt[2] >= 0.f) && (xt[2] <= 1.f) && (xt[3] >= 0.f) && (xt[3] <= 1.f);
        float xtv = (g == 1) ? xt[1] : xt[0];
        xtv = (g == 2) ? xt[2] : xtv;
        xtv = (g == 3) ? xt[3] : xtv;
        const int ti = ((g >> p) << (p + 1)) | (tb << p) | (g & lm);

        float ov[31];
        {
            const float* ob = op + col16 * 124 + g * 31;
            #pragma unroll
            for (int j = 0; j < 31; ++j) ov[j] = ob[j];
        }

        // widths
        float mw = ov[0];
        #pragma unroll
        for (int k = 1; k < 10; ++k) mw = fmaxf(mw, ov[k]);
        float ew[10], sw = 0.f;
        #pragma unroll
        for (int k = 0; k < 10; ++k) { ew[k] = __expf(ov[k] - mw); sw += ew[k]; }
        const float fw = 0.99f / sw;
        float Cw[11];
        Cw[0] = 0.f;
        #pragma unroll
        for (int k = 1; k <= 10; ++k) Cw[k] = Cw[k - 1] + (0.001f + ew[k - 1] * fw);
        Cw[10] = 1.0f;
        float Wd[10];
        #pragma unroll
        for (int k = 0; k < 10; ++k) Wd[k] = Cw[k + 1] - Cw[k];

        // heights
        float mh = ov[10];
        #pragma unroll
        for (int k = 1; k < 10; ++k) mh = fmaxf(mh, ov[10 + k]);
        float eh[10], sh = 0.f;
        #pragma unroll
        for (int k = 0; k < 10; ++k) { eh[k] = __expf(ov[10 + k] - mh); sh += eh[k]; }
        const float fh = 0.99f / sh;
        float Ch[11];
        Ch[0] = 0.f;
        #pragma unroll
        for (int k = 1; k <= 10; ++k) Ch[k] = Ch[k - 1] + (0.001f + eh[k - 1] * fh);
        Ch[10] = 1.0f;
        float Hh[10];
        #pragma unroll
        for (int k = 0; k < 10; ++k) Hh[k] = Ch[k + 1] - Ch[k];

        // derivatives
        float dv[11];
        #pragma unroll
        for (int k = 0; k < 11; ++k) {
            const float u = ov[20 + k];
            const float sp = (u > 15.f) ? u : __logf(1.f + __expf(u));
            dv[k] = (0.001f + sp) * DNORM;
        }

        // bin search + gathers via compare-select scan
        const float xin = fminf(fmaxf(xtv, 0.f), 1.f);
        float in_cw = 0.f, in_bw = Wd[0], in_ch = 0.f, in_h = Hh[0];
        float in_d = dv[0], in_dp1 = dv[1];
        #pragma unroll
        for (int k = 1; k < 10; ++k) {
            const bool ge = (xin >= Cw[k]);
            in_cw  = ge ? Cw[k]     : in_cw;
            in_bw  = ge ? Wd[k]     : in_bw;
            in_ch  = ge ? Ch[k]     : in_ch;
            in_h   = ge ? Hh[k]     : in_h;
            in_d   = ge ? dv[k]     : in_d;
            in_dp1 = ge ? dv[k + 1] : in_dp1;
        }

        const float th   = (xin - in_cw) / in_bw;
        const float tomt = th * (1.f - th);
        const float dl   = in_h / in_bw;
        const float nume = in_h * (dl * th * th + in_d * tomt);
        const float deno = dl + (in_d + in_dp1 - 2.f * dl) * tomt;
        const float xout = in_ch + nume / deno;
        const float omt  = 1.f - th;
        const float dnum = dl * dl * (in_dp1 * th * th + 2.f * dl * tomt + in_d * omt * omt);
        const float lad  = __logf(dnum) - 2.f * __logf(deno);

        jacl += inside ? lad : 0.f;
        s_x[srow * 9 + ti] = inside ? xout : xtv;
    }

    // jac = sum over the 4 trafo-slot lanes of each sample
    jacl += __shfl_xor(jacl, 16);
    jacl += __shfl_xor(jacl, 32);
    if (ln < 16) {
        const int smp = wgBase + wv * 16 + ln;
        if (smp < n) JAC[smp] = jacl;
    }
}

extern "C" void kernel_launch(void* const* d_in, const int* in_sizes, int n_in,
                              void* d_out, int out_size, void* d_ws, size_t ws_size,
                              hipStream_t stream) {
    (void)n_in; (void)ws_size;
    const float* X  = (const float*)d_in[0];
    const float* C4 = (const float*)d_in[1];
    const float* W1 = (const float*)d_in[2];
    const float* B1 = (const float*)d_in[3];
    const float* W2 = (const float*)d_in[4];
    const float* B2 = (const float*)d_in[5];
    const float* W3 = (const float*)d_in[6];
    const float* B3 = (const float*)d_in[7];
    float* out = (float*)d_out;
    unsigned short* wsf = (unsigned short*)d_ws;   // 6 * 32768 u16 = 384 KB

    hipLaunchKernelGGL(prep_kernel, dim3(NBLK), dim3(1024), 0, stream,
                       W1, B1, W2, B2, W3, B3, wsf);

    const int n = in_sizes[0] / 8;                 // 262144
    const int grid = (n + WGS - 1) / WGS;          // 1093
    hipLaunchKernelGGL(flow_kernel, dim3(grid), dim3(TPB), 0, stream,
                       X, C4, wsf, out, n);
}

// Round 13
// 193.525 us; speedup vs baseline: 14.6247x; 1.1981x over previous
//
#include <hip/hip_runtime.h>
#include <hip/hip_bf16.h>
#include <math.h>

#define TPB 960
#define WGS 240              // samples per workgroup (15 waves x 16)
#define NBLK 6
#define SW_U16 14848         // staged weights+bias content (u16 units)
#define CHUNKS 29            // SW_U16 / 512
#define DNORM (1.0f / (0.001f + 0.69314718055994530942f))

typedef float  f32x4  __attribute__((ext_vector_type(4)));
typedef short  bf16x8 __attribute__((ext_vector_type(8)));

#define MFMA16(A, B, C) __builtin_amdgcn_mfma_f32_16x16x32_bf16((A), (B), (C), 0, 0, 0)

// d_ws per-flow-block region: stride 32768 u16 = 64KB (content 14848 u16)
//   W1 hi : u16 [0 .. 2047]      (4 frags x 512; K=8 zero-padded; bf16-only)
//   W2 hi : u16 [2048 .. 6143]   (8 frags; bf16-only)
//   W3 hi : u16 [6144 .. 14335]  (16 frags; bf16-only, col>=124 zeroed)
//   bias  : f32 [256] at u16 14336 (b1 64 | b2 64 | b3p 128)
// UNPERMUTED (round-7 proven): fragment position 16*tile + (lane&15) = real col.

__device__ __forceinline__ float leaky(float a) { return a >= 0.f ? a : 0.01f * a; }

__device__ __forceinline__ unsigned int bfbits(float f) {
    unsigned int u = __float_as_uint(f);
    return (u + 0x7fffu + ((u >> 16) & 1u)) >> 16;   // RNE to bf16 (prep only)
}

// packed bf16x2 via v_cvt_pk_bf16_f32 (RNE, matches bfbits)
__device__ __forceinline__ unsigned int pkcvt(float a, float b) {
    __hip_bfloat162 t = __float22bfloat162_rn(make_float2(a, b));
    union { __hip_bfloat162 b2; unsigned int u; } cv;
    cv.b2 = t;
    return cv.u;
}

__global__ void prep_kernel(const float* __restrict__ W1, const float* __restrict__ B1,
                            const float* __restrict__ W2, const float* __restrict__ B2,
                            const float* __restrict__ W3, const float* __restrict__ B3,
                            unsigned short* __restrict__ wsf)
{
    const int blk = blockIdx.x;
    const int tid = threadIdx.x;          // 1024 threads
    unsigned short* base = wsf + blk * 32768;
    const float* w1 = W1 + blk * 512;
    const float* w2 = W2 + blk * 4096;
    const float* w3 = W3 + blk * 7936;

    for (int e = tid; e < 2048; e += 1024) {
        const int tile = e >> 9, lane = (e >> 3) & 63, i = e & 7;
        const int k = (lane >> 4) * 8 + i, col = tile * 16 + (lane & 15);
        const float f = (k < 8) ? w1[k * 64 + col] : 0.f;
        base[e] = (unsigned short)bfbits(f);                         // W1 hi only
    }
    for (int e = tid; e < 4096; e += 1024) {
        const int ks = e >> 11, tile = (e >> 9) & 3, lane = (e >> 3) & 63, i = e & 7;
        const int k = ks * 32 + (lane >> 4) * 8 + i, col = tile * 16 + (lane & 15);
        base[2048 + e] = (unsigned short)bfbits(w2[k * 64 + col]);   // W2 hi only
    }
    for (int e = tid; e < 8192; e += 1024) {
        const int ks = e >> 12, tile = (e >> 9) & 7, lane = (e >> 3) & 63, i = e & 7;
        const int k = ks * 32 + (lane >> 4) * 8 + i, col = tile * 16 + (lane & 15);
        const float f = (col < 124) ? w3[k * 124 + col] : 0.f;
        base[6144 + e] = (unsigned short)bfbits(f);                  // W3 hi only
    }
    float* bb = reinterpret_cast<float*>(base + 14336);
    if (tid < 64) { bb[tid] = B1[blk * 64 + tid]; bb[64 + tid] = B2[blk * 64 + tid]; }
    if (tid >= 128 && tid < 256) {
        const int j = tid - 128;
        bb[128 + j] = (j < 124) ? B3[blk * 124 + j] : 0.f;
    }
}

__global__ __launch_bounds__(TPB, 4) void flow_kernel(
    const float* __restrict__ X, const float* __restrict__ C4,
    const unsigned short* __restrict__ WSF, float* __restrict__ JAC, int n)
{
    // 157,376 B static LDS -> 1 WG/CU, 15 waves/CU
    __shared__ __align__(16) unsigned short s_w[SW_U16];  // 29KB: W1|W2|W3 hi + bias(f32)
    __shared__ __align__(16) unsigned char  s_u[119040];  // 15 waves x 7936B: union{ h[16][72] bf16, o[16][124] f32 }
    __shared__ __align__(16) float          s_x[2160];    // [240][9] f32 (pad 9 -> conflict-free)

    const int tid   = threadIdx.x;
    const int wv    = tid >> 6;        // 0..14
    const int ln    = tid & 63;
    const int col16 = ln & 15;         // MFMA col = SAMPLE slot
    const int g     = ln >> 4;         // k-group / feature-row group / trafo slot
    const int srow  = wv * 16 + col16; // this lane's sample row (0..239)
    const int wgBase = blockIdx.x * WGS;

    unsigned short* hh = reinterpret_cast<unsigned short*>(s_u + wv * 7936); // [16][72] bf16
    float*          op = reinterpret_cast<float*>(s_u + wv * 7936);          // [16][124] f32 (overlays hh)

    // ---- initial x load -> LDS (stride-9, tail-guarded); c stays in registers
    {
        const int s   = tid >> 2;            // 0..239
        const int d0  = (tid & 3) * 2;
        const int smp = wgBase + s;
        float2 xv = make_float2(0.5f, 0.5f);
        if (smp < n)
            xv = reinterpret_cast<const float2*>(X)[(size_t)smp * 4 + (tid & 3)];
        s_x[s * 9 + d0]     = xv.x;
        s_x[s * 9 + d0 + 1] = xv.y;
    }
    float4 cvv = make_float4(0.f, 0.f, 0.f, 0.f);
    if (wgBase + srow < n)
        cvv = reinterpret_cast<const float4*>(C4)[(size_t)wgBase + srow];

    // ---- stage block 0 weights (29 chunks x 1024B over 15 waves)
    {
        const unsigned short* gsrc = WSF;
        #pragma unroll
        for (int r = 0; r < 2; ++r) {
            const int ch = r * 15 + wv;
            if (ch < CHUNKS) {
                const int off = ch * 512;   // u16 units, wave-uniform
                __builtin_amdgcn_global_load_lds(
                    (const __attribute__((address_space(1))) unsigned int*)(gsrc + off + ln * 8),
                    (__attribute__((address_space(3))) unsigned int*)(&s_w[off]),
                    16, 0, 0);
            }
        }
    }

    const float* biasf = reinterpret_cast<const float*>(&s_w[14336]);
    const int fB = g * 4;              // this lane's feature offset within a 16-row tile
    float jacl = 0.f;

    #pragma unroll 1
    for (int blk = 0; blk < NBLK; ++blk) {
        __syncthreads();   // staged weights visible; per-wave scratch free

        const int p  = blk >> 1;
        const int cb = (blk & 1) ^ 1;
        const int tb = blk & 1;
        const int lm = (1 << p) - 1;

        // ---- conditioning inputs: x[cond dims] ++ c, bf16 (B-operand, k<8 => g==0)
        float xcf[8];
        #pragma unroll
        for (int j = 0; j < 4; ++j) {
            const int cd = ((j >> p) << (p + 1)) | (cb << p) | (j & lm);
            xcf[j] = s_x[srow * 9 + cd];
        }
        xcf[4] = cvv.x; xcf[5] = cvv.y; xcf[6] = cvv.z; xcf[7] = cvv.w;

        union { unsigned int u[4]; bf16x8 v; } bxh;
        #pragma unroll
        for (int q = 0; q < 4; ++q)
            bxh.u[q] = (g == 0) ? pkcvt(xcf[2 * q], xcf[2 * q + 1]) : 0u;

        // ---- L1: D^T = W1^T(16f x 32k) * x(32k x 16s), bf16-only
        #pragma unroll
        for (int tile = 0; tile < 4; ++tile) {
            f32x4 a1 = *reinterpret_cast<const f32x4*>(&biasf[tile * 16 + fB]);
            const bf16x8 wh = *reinterpret_cast<const bf16x8*>(&s_w[tile * 512 + ln * 8]);
            a1 = MFMA16(wh, bxh.v, a1);
            uint2 pw;
            pw.x = pkcvt(leaky(a1[0]), leaky(a1[1]));
            pw.y = pkcvt(leaky(a1[2]), leaky(a1[3]));
            *reinterpret_cast<uint2*>(&hh[col16 * 72 + tile * 16 + fB]) = pw;  // ds_write_b64
        }

        // ---- L2: 64 -> 64 (h1 bf16, W2 bf16-only)
        f32x4 acc2[4];
        #pragma unroll
        for (int tile = 0; tile < 4; ++tile)
            acc2[tile] = *reinterpret_cast<const f32x4*>(&biasf[64 + tile * 16 + fB]);
        #pragma unroll
        for (int ks = 0; ks < 2; ++ks) {
            const bf16x8 hf = *reinterpret_cast<const bf16x8*>(&hh[col16 * 72 + ks * 32 + g * 8]);
            #pragma unroll
            for (int tile = 0; tile < 4; ++tile) {
                const bf16x8 wh = *reinterpret_cast<const bf16x8*>(
                    &s_w[2048 + (ks * 4 + tile) * 512 + ln * 8]);
                acc2[tile] = MFMA16(wh, hf, acc2[tile]);
            }
        }
        #pragma unroll
        for (int tile = 0; tile < 4; ++tile) {
            uint2 pw;
            pw.x = pkcvt(leaky(acc2[tile][0]), leaky(acc2[tile][1]));
            pw.y = pkcvt(leaky(acc2[tile][2]), leaky(acc2[tile][3]));
            *reinterpret_cast<uint2*>(&hh[col16 * 72 + tile * 16 + fB]) = pw;
        }

        // ---- L3: 64 -> 124 (padded 128; h2 bf16, W3 bf16-only)
        f32x4 acc3[8];
        #pragma unroll
        for (int tile = 0; tile < 8; ++tile)
            acc3[tile] = *reinterpret_cast<const f32x4*>(&biasf[128 + tile * 16 + fB]);
        #pragma unroll
        for (int ks = 0; ks < 2; ++ks) {
            const bf16x8 hf = *reinterpret_cast<const bf16x8*>(&hh[col16 * 72 + ks * 32 + g * 8]);
            #pragma unroll
            for (int tile = 0; tile < 8; ++tile) {
                const bf16x8 wh = *reinterpret_cast<const bf16x8*>(
                    &s_w[6144 + (ks * 8 + tile) * 512 + ln * 8]);
                acc3[tile] = MFMA16(wh, hf, acc3[tile]);
            }
        }

        __syncthreads();   // all waves done reading s_w

        // ---- issue next block's weight staging (overlaps o-transpose + spline)
        if (blk < NBLK - 1) {
            const unsigned short* gsrc = WSF + (blk + 1) * 32768;
            #pragma unroll
            for (int r = 0; r < 2; ++r) {
                const int ch = r * 15 + wv;
                if (ch < CHUNKS) {
                    const int off = ch * 512;
                    __builtin_amdgcn_global_load_lds(
                        (const __attribute__((address_space(1))) unsigned int*)(gsrc + off + ln * 8),
                        (__attribute__((address_space(3))) unsigned int*)(&s_w[off]),
                        16, 0, 0);
                }
            }
        }

        // ---- o transpose: lane writes its 4 consecutive features per tile (b128)
        #pragma unroll
        for (int tile = 0; tile < 8; ++tile)
            if (tile * 16 + fB < 124)
                *reinterpret_cast<f32x4*>(&op[col16 * 124 + tile * 16 + fB]) = acc3[tile];

        // ---- spline: lane = (sample col16, trafo slot g)
        float xt[4];
        #pragma unroll
        for (int j = 0; j < 4; ++j) {
            const int td = ((j >> p) << (p + 1)) | (tb << p) | (j & lm);
            xt[j] = s_x[srow * 9 + td];
        }
        const float xmn = fminf(fminf(xt[0], xt[1]), fminf(xt[2], xt[3]));
        const float xmx = fmaxf(fmaxf(xt[0], xt[1]), fmaxf(xt[2], xt[3]));
        const bool inside = (xmn >= 0.f) && (xmx <= 1.f);
        float xtv = (g == 1) ? xt[1] : xt[0];
        xtv = (g == 2) ? xt[2] : xtv;
        xtv = (g == 3) ? xt[3] : xtv;
        const int ti = ((g >> p) << (p + 1)) | (tb << p) | (g & lm);

        float ov[31];
        {
            const float* ob = op + col16 * 124 + g * 31;
            #pragma unroll
            for (int j = 0; j < 31; ++j) ov[j] = ob[j];
        }

        // widths: softmax WITHOUT max-subtraction (sigma(o)~0.15, overflow needs ~580 sigma)
        float ew[10];
        #pragma unroll
        for (int k = 0; k < 10; ++k) ew[k] = __expf(ov[k]);
        const float sw = (((ew[0] + ew[1]) + (ew[2] + ew[3])) + ((ew[4] + ew[5]) + (ew[6] + ew[7])))
                         + (ew[8] + ew[9]);
        const float fw = 0.99f / sw;
        float Cw[11];
        Cw[0] = 0.f;
        #pragma unroll
        for (int k = 1; k <= 9; ++k) Cw[k] = Cw[k - 1] + (0.001f + ew[k - 1] * fw);
        Cw[10] = 1.0f;

        // heights: same form
        float eh[10];
        #pragma unroll
        for (int k = 0; k < 10; ++k) eh[k] = __expf(ov[10 + k]);
        const float sh = (((eh[0] + eh[1]) + (eh[2] + eh[3])) + ((eh[4] + eh[5]) + (eh[6] + eh[7])))
                         + (eh[8] + eh[9]);
        const float fh = 0.99f / sh;
        float Ch[11];
        Ch[0] = 0.f;
        #pragma unroll
        for (int k = 1; k <= 9; ++k) Ch[k] = Ch[k - 1] + (0.001f + eh[k - 1] * fh);
        Ch[10] = 1.0f;

        // scan: select knot pairs + RAW derivative inputs (softplus applied lazily after)
        const float xin = fminf(fmaxf(xtv, 0.f), 1.f);
        float in_cw = 0.f, in_cwp1 = Cw[1], in_ch = 0.f, in_chp1 = Ch[1];
        float u_d = ov[20], u_dp1 = ov[21];
        #pragma unroll
        for (int k = 1; k < 10; ++k) {
            const bool ge = (xin >= Cw[k]);
            in_cw   = ge ? Cw[k]      : in_cw;
            in_cwp1 = ge ? Cw[k + 1]  : in_cwp1;
            in_ch   = ge ? Ch[k]      : in_ch;
            in_chp1 = ge ? Ch[k + 1]  : in_chp1;
            u_d     = ge ? ov[20 + k] : u_d;
            u_dp1   = ge ? ov[21 + k] : u_dp1;
        }
        const float in_bw = in_cwp1 - in_cw;
        const float in_h  = in_chp1 - in_ch;
        const float sp_d   = (u_d   > 15.f) ? u_d   : __logf(1.f + __expf(u_d));
        const float sp_dp1 = (u_dp1 > 15.f) ? u_dp1 : __logf(1.f + __expf(u_dp1));
        const float in_d   = (0.001f + sp_d)   * DNORM;
        const float in_dp1 = (0.001f + sp_dp1) * DNORM;

        const float th   = (xin - in_cw) / in_bw;
        const float tomt = th * (1.f - th);
        const float dl   = in_h / in_bw;
        const float nume = in_h * (dl * th * th + in_d * tomt);
        const float deno = dl + (in_d + in_dp1 - 2.f * dl) * tomt;
        const float xout = in_ch + nume / deno;
        const float omt  = 1.f - th;
        const float dnum = dl * dl * (in_dp1 * th * th + 2.f * dl * tomt + in_d * omt * omt);
        const float lad  = __logf(dnum) - 2.f * __logf(deno);

        jacl += inside ? lad : 0.f;
        s_x[srow * 9 + ti] = inside ? xout : xtv;
    }

    // jac = sum over the 4 trafo-slot lanes of each sample
    jacl += __shfl_xor(jacl, 16);
    jacl += __shfl_xor(jacl, 32);
    if (ln < 16) {
        const int smp = wgBase + wv * 16 + ln;
        if (smp < n) JAC[smp] = jacl;
    }
}

extern "C" void kernel_launch(void* const* d_in, const int* in_sizes, int n_in,
                              void* d_out, int out_size, void* d_ws, size_t ws_size,
                              hipStream_t stream) {
    (void)n_in; (void)ws_size;
    const float* X  = (const float*)d_in[0];
    const float* C4 = (const float*)d_in[1];
    const float* W1 = (const float*)d_in[2];
    const float* B1 = (const float*)d_in[3];
    const float* W2 = (const float*)d_in[4];
    const float* B2 = (const float*)d_in[5];
    const float* W3 = (const float*)d_in[6];
    const float* B3 = (const float*)d_in[7];
    float* out = (float*)d_out;
    unsigned short* wsf = (unsigned short*)d_ws;   // 6 * 32768 u16 = 384 KB

    hipLaunchKernelGGL(prep_kernel, dim3(NBLK), dim3(1024), 0, stream,
                       W1, B1, W2, B2, W3, B3, wsf);

    const int n = in_sizes[0] / 8;                 // 262144
    const int grid = (n + WGS - 1) / WGS;          // 1093
    hipLaunchKernelGGL(flow_kernel, dim3(grid), dim3(TPB), 0, stream,
                       X, C4, wsf, out, n);
}